// Round 2
// baseline (338.926 us; speedup 1.0000x reference)
//
#include <hip/hip_runtime.h>
#include <math.h>

// Problem: b=2, h=8, n=1024, d=64, DIM=512. Inputs/outputs FLOAT32.
// Internal pipeline bf16 MFMA (f32 accumulate). SCALE = 1/8.

typedef __bf16 bf16x8 __attribute__((ext_vector_type(8)));
typedef float f32x4 __attribute__((ext_vector_type(4)));

#define SCALE 0.125f

__device__ __forceinline__ unsigned short f2bf(float f){
  unsigned int x = __builtin_bit_cast(unsigned int, f);
  unsigned int r = (x + 0x7fffu + ((x >> 16) & 1u)) >> 16;  // RNE
  return (unsigned short)r;
}
__device__ __forceinline__ f32x4 mfma16(bf16x8 a, bf16x8 b, f32x4 c){
  return __builtin_amdgcn_mfma_f32_16x16x32_bf16(a, b, c, 0, 0, 0);
}
__device__ __forceinline__ bf16x8 ld8(const unsigned short* p){
  return *(const bf16x8*)p;
}

// ---------------- K0: f32->bf16 convert x, and transpose+convert 7 weights --
__global__ __launch_bounds__(256) void k_prep(
    const float* __restrict__ x,
    const float* __restrict__ w0, const float* __restrict__ w1,
    const float* __restrict__ w2, const float* __restrict__ w3,
    const float* __restrict__ w4, const float* __restrict__ w5,
    const float* __restrict__ w6,
    unsigned short* __restrict__ xb, unsigned short* __restrict__ wT){
  int idx = blockIdx.x * 256 + threadIdx.x;   // 1048576 + 7*262144 total
  if (idx < 1048576){
    xb[idx] = f2bf(x[idx]);
    return;
  }
  int r2 = idx - 1048576;
  int t = r2 >> 18;
  int rem = r2 & 262143;
  int k = rem >> 9, c = rem & 511;
  const float* src;
  switch (t){
    case 0: src = w0; break; case 1: src = w1; break; case 2: src = w2; break;
    case 3: src = w3; break; case 4: src = w4; break; case 5: src = w5; break;
    default: src = w6; break;
  }
  wT[(size_t)t*262144 + (size_t)c*512 + k] = f2bf(src[(size_t)k*512 + c]);
}

// ---------------- K1: 6 projections  P[t][bh][n][d] = x @ w_t  --------------
// wave = 16(M) x 64(N) tile, K=512. A=xb [2048,512], Bt=wT[t] [512,512].
__global__ __launch_bounds__(256) void k_proj(
    const unsigned short* __restrict__ xb, const unsigned short* __restrict__ wT,
    unsigned short* __restrict__ P, unsigned short* __restrict__ vcT){
  int gw = (blockIdx.x * 256 + threadIdx.x) >> 6;     // 6144 waves
  int lane = threadIdx.x & 63, l16 = lane & 15, quad = lane >> 4;
  int nt = gw & 7, mt = (gw >> 3) & 127, t = gw >> 10;
  int m0 = mt * 16, n0 = nt * 64;
  const unsigned short* Bt = wT + (size_t)t * 262144;
  f32x4 acc[4] = {};
  for (int k0 = 0; k0 < 512; k0 += 32){
    bf16x8 a = ld8(xb + (size_t)(m0 + l16) * 512 + k0 + quad * 8);
#pragma unroll
    for (int f = 0; f < 4; ++f){
      bf16x8 b = ld8(Bt + (size_t)(n0 + f*16 + l16) * 512 + k0 + quad * 8);
      acc[f] = mfma16(a, b, acc[f]);
    }
  }
#pragma unroll
  for (int f = 0; f < 4; ++f){
    int col = n0 + f*16 + l16;
    int h = col >> 6, d = col & 63;
#pragma unroll
    for (int r = 0; r < 4; ++r){
      int row = m0 + quad*4 + r;
      int b_ = row >> 10, n_ = row & 1023;
      int bh = b_*8 + h;
      unsigned short v = f2bf(acc[f][r]);
      P[(size_t)(t*16 + bh) * 65536 + (size_t)n_ * 64 + d] = v;
      if (t == 5) vcT[(size_t)bh * 65536 + (size_t)d * 1024 + n_] = v;  // v_c^T
    }
  }
}

// ---------------- K2: term1[i][j] (lower-tri) and sig[k][j] (strict upper) --
// term1 = tril(q_c @ v_u^T * s);  sig = sigmoid(strict-upper(q_u @ k_u^T * s))
// wave = 16 x 64 tile, K=64.
__global__ __launch_bounds__(256) void k_qk(
    const unsigned short* __restrict__ P,
    unsigned short* __restrict__ term1, unsigned short* __restrict__ sig){
  int gw = (blockIdx.x * 256 + threadIdx.x) >> 6;     // 32768 waves
  int lane = threadIdx.x & 63, l16 = lane & 15, quad = lane >> 4;
  int nt = gw & 15, mt = (gw >> 4) & 63, mat = (gw >> 10) & 1, bh = gw >> 11;
  int m0 = mt * 16, n0 = nt * 64;
  unsigned short* out = (mat ? sig : term1) + (size_t)bh * 1048576;
  bool zero_tile = mat ? (n0 + 63 <= m0) : (n0 > m0 + 15);
  if (zero_tile){
#pragma unroll
    for (int f = 0; f < 4; ++f){
      int col = n0 + f*16 + l16;
#pragma unroll
      for (int r = 0; r < 4; ++r)
        out[(size_t)(m0 + quad*4 + r) * 1024 + col] = 0;
    }
    return;
  }
  const unsigned short* A  = P + (size_t)((mat ? 0 : 3)*16 + bh) * 65536;
  const unsigned short* Bt = P + (size_t)((mat ? 1 : 2)*16 + bh) * 65536;
  f32x4 acc[4] = {};
  for (int k0 = 0; k0 < 64; k0 += 32){
    bf16x8 a = ld8(A + (size_t)(m0 + l16) * 64 + k0 + quad * 8);
#pragma unroll
    for (int f = 0; f < 4; ++f){
      bf16x8 b = ld8(Bt + (size_t)(n0 + f*16 + l16) * 64 + k0 + quad * 8);
      acc[f] = mfma16(a, b, acc[f]);
    }
  }
#pragma unroll
  for (int f = 0; f < 4; ++f){
    int col = n0 + f*16 + l16;
#pragma unroll
    for (int r = 0; r < 4; ++r){
      int row = m0 + quad*4 + r;
      float v = acc[f][r] * SCALE;
      float o;
      if (mat == 0) o = (col <= row) ? v : 0.f;
      else          o = (col >  row) ? 1.f / (1.f + expf(-v)) : 0.f;
      out[(size_t)row * 1024 + col] = f2bf(o);
    }
  }
}

// ---------------- K3: fin = S_c_masked - silu(S_u)  (fin is FLOAT32) --------
// S_u[i,k] = sum_j term1[i,j]*sig[k,j]  (A.B^T form, both stored row-major)
// S_c fused in-register (K=64 with q_c,k_c). wave = 32(M) x 64(N).
__global__ __launch_bounds__(256) void k_scores(
    const unsigned short* __restrict__ P, const unsigned short* __restrict__ term1,
    const unsigned short* __restrict__ sig, float* __restrict__ fin){
  int gw = (blockIdx.x * 256 + threadIdx.x) >> 6;     // 8192 waves
  int lane = threadIdx.x & 63, l16 = lane & 15, quad = lane >> 4;
  int nt = gw & 15, mt = (gw >> 4) & 31, bh = gw >> 9;
  int m0 = mt * 32, n0 = nt * 64;
  size_t sbase = (size_t)bh * 1048576;
  float* out = fin + sbase;
  if (n0 > m0 + 31){          // whole tile above diagonal -> -inf
#pragma unroll
    for (int half = 0; half < 2; ++half)
#pragma unroll
      for (int f = 0; f < 4; ++f)
#pragma unroll
        for (int r = 0; r < 4; ++r)
          out[(size_t)(m0 + half*16 + quad*4 + r) * 1024 + (n0 + f*16 + l16)] = -INFINITY;
    return;
  }
  const unsigned short* A  = term1 + sbase;
  const unsigned short* Bt = sig + sbase;
  f32x4 au[2][4] = {};
  for (int j0 = n0; j0 <= m0; j0 += 32){              // triangular j-range
    bf16x8 a0 = ld8(A + (size_t)(m0      + l16) * 1024 + j0 + quad * 8);
    bf16x8 a1 = ld8(A + (size_t)(m0 + 16 + l16) * 1024 + j0 + quad * 8);
#pragma unroll
    for (int f = 0; f < 4; ++f){
      bf16x8 b = ld8(Bt + (size_t)(n0 + f*16 + l16) * 1024 + j0 + quad * 8);
      au[0][f] = mfma16(a0, b, au[0][f]);
      au[1][f] = mfma16(a1, b, au[1][f]);
    }
  }
  const unsigned short* Qc = P + (size_t)(3*16 + bh) * 65536;
  const unsigned short* Kc = P + (size_t)(4*16 + bh) * 65536;
  f32x4 ac[2][4] = {};
  for (int k0 = 0; k0 < 64; k0 += 32){
    bf16x8 a0 = ld8(Qc + (size_t)(m0      + l16) * 64 + k0 + quad * 8);
    bf16x8 a1 = ld8(Qc + (size_t)(m0 + 16 + l16) * 64 + k0 + quad * 8);
#pragma unroll
    for (int f = 0; f < 4; ++f){
      bf16x8 b = ld8(Kc + (size_t)(n0 + f*16 + l16) * 64 + k0 + quad * 8);
      ac[0][f] = mfma16(a0, b, ac[0][f]);
      ac[1][f] = mfma16(a1, b, ac[1][f]);
    }
  }
#pragma unroll
  for (int half = 0; half < 2; ++half)
#pragma unroll
    for (int f = 0; f < 4; ++f){
      int col = n0 + f*16 + l16;
#pragma unroll
      for (int r = 0; r < 4; ++r){
        int row = m0 + half*16 + quad*4 + r;
        if (col > row){
          out[(size_t)row * 1024 + col] = -INFINITY;
        } else {
          float su = au[half][f][r];
          float sc = ac[half][f][r] * SCALE;
          float silu = su / (1.f + expf(-su));
          out[(size_t)row * 1024 + col] = sc - silu;
        }
      }
    }
}

// ---------------- K4a: row softmax (f32 fin -> bf16 probs) ------------------
__global__ __launch_bounds__(256) void k_softmax(
    const float* __restrict__ fin, unsigned short* __restrict__ probs){
  size_t row = blockIdx.x;                 // 16384 rows
  const float* p = fin + row * 1024;
  int tid = threadIdx.x;
  float4 raw = ((const float4*)p)[tid];
  float v0 = raw.x, v1 = raw.y, v2 = raw.z, v3 = raw.w;
  float m = fmaxf(fmaxf(v0, v1), fmaxf(v2, v3));
#pragma unroll
  for (int off = 32; off > 0; off >>= 1) m = fmaxf(m, __shfl_down(m, off));
  __shared__ float sm[4], ss[4];
  int w = tid >> 6, lane = tid & 63;
  if (lane == 0) sm[w] = m;
  __syncthreads();
  float rm = fmaxf(fmaxf(sm[0], sm[1]), fmaxf(sm[2], sm[3]));
  float e0 = expf(v0 - rm), e1 = expf(v1 - rm), e2 = expf(v2 - rm), e3 = expf(v3 - rm);
  float s = e0 + e1 + e2 + e3;
#pragma unroll
  for (int off = 32; off > 0; off >>= 1) s += __shfl_down(s, off);
  if (lane == 0) ss[w] = s;
  __syncthreads();
  float inv = 1.f / (ss[0] + ss[1] + ss[2] + ss[3]);
  ushort4 o;
  o.x = f2bf(e0 * inv); o.y = f2bf(e1 * inv); o.z = f2bf(e2 * inv); o.w = f2bf(e3 * inv);
  ((ushort4*)(probs + row * 1024))[tid] = o;
}

// ---------------- K4b: O[bh][n][d] = probs @ v_c ----------------------------
// wave = 16(M) x 64(N=d), K<=1024 (triangular: cols <= row; beyond-row probs are 0).
__global__ __launch_bounds__(256) void k_pv(
    const unsigned short* __restrict__ probs, const unsigned short* __restrict__ vcT,
    unsigned short* __restrict__ O){
  int gw = (blockIdx.x * 256 + threadIdx.x) >> 6;     // 1024 waves
  int lane = threadIdx.x & 63, l16 = lane & 15, quad = lane >> 4;
  int mt = gw & 63, bh = gw >> 6;
  int m0 = mt * 16;
  const unsigned short* A  = probs + (size_t)bh * 1048576;
  const unsigned short* Bt = vcT + (size_t)bh * 65536;
  f32x4 acc[4] = {};
  for (int k0 = 0; k0 <= m0 + 15; k0 += 32){
    bf16x8 a = ld8(A + (size_t)(m0 + l16) * 1024 + k0 + quad * 8);
#pragma unroll
    for (int f = 0; f < 4; ++f){
      bf16x8 b = ld8(Bt + (size_t)(f*16 + l16) * 1024 + k0 + quad * 8);
      acc[f] = mfma16(a, b, acc[f]);
    }
  }
#pragma unroll
  for (int f = 0; f < 4; ++f)
#pragma unroll
    for (int r = 0; r < 4; ++r)
      O[(size_t)bh * 65536 + (size_t)(m0 + quad*4 + r) * 64 + (f*16 + l16)] = f2bf(acc[f][r]);
}

// ---------------- K5: out(f32) = O_cat[2048,512] @ w_out --------------------
__global__ __launch_bounds__(256) void k_out(
    const unsigned short* __restrict__ O, const unsigned short* __restrict__ woT,
    float* __restrict__ out){
  int gw = (blockIdx.x * 256 + threadIdx.x) >> 6;     // 1024 waves
  int lane = threadIdx.x & 63, l16 = lane & 15, quad = lane >> 4;
  int nt = gw & 7, mt = gw >> 3;
  int m0 = mt * 16, n0 = nt * 64;
  int r_ = m0 + l16;
  int b_ = r_ >> 10, n_ = r_ & 1023;
  f32x4 acc[4] = {};
  for (int k0 = 0; k0 < 512; k0 += 32){
    int k = k0 + quad * 8;
    int h = k >> 6, dd = k & 63;
    bf16x8 a = ld8(O + (size_t)(b_*8 + h) * 65536 + (size_t)n_ * 64 + dd);
#pragma unroll
    for (int f = 0; f < 4; ++f){
      bf16x8 b = ld8(woT + (size_t)(n0 + f*16 + l16) * 512 + k0 + quad * 8);
      acc[f] = mfma16(a, b, acc[f]);
    }
  }
#pragma unroll
  for (int f = 0; f < 4; ++f)
#pragma unroll
    for (int r = 0; r < 4; ++r)
      out[(size_t)(m0 + quad*4 + r) * 512 + (n0 + f*16 + l16)] = acc[f][r];
}

extern "C" void kernel_launch(void* const* d_in, const int* in_sizes, int n_in,
                              void* d_out, int out_size, void* d_ws, size_t ws_size,
                              hipStream_t stream){
  const float* x = (const float*)d_in[0];
  float* out = (float*)d_out;
  unsigned short* ws = (unsigned short*)d_ws;

  // workspace layout (u16 elements unless noted):
  unsigned short* wT    = ws;                                   // 7*262144
  unsigned short* xb    = wT    + (size_t)7  * 262144;          // 1048576
  unsigned short* P     = xb    + (size_t)1048576;              // 96*65536
  unsigned short* vcT   = P     + (size_t)96 * 65536;           // 16*65536
  unsigned short* term1 = vcT   + (size_t)16 * 65536;           // 16*1048576 (reused as probs)
  unsigned short* sig   = term1 + (size_t)16 * 1048576;         // 16*1048576
  unsigned short* O     = sig   + (size_t)16 * 1048576;         // 16*65536
  float*          fin   = (float*)(O + (size_t)16 * 65536);     // 16*1048576 f32
  unsigned short* probs = term1;                                 // reuse (dead after k_scores)

  k_prep<<<11264, 256, 0, stream>>>(
      x,
      (const float*)d_in[1], (const float*)d_in[2], (const float*)d_in[3],
      (const float*)d_in[4], (const float*)d_in[5], (const float*)d_in[6],
      (const float*)d_in[7], xb, wT);
  k_proj<<<1536, 256, 0, stream>>>(xb, wT, P, vcT);
  k_qk<<<8192, 256, 0, stream>>>(P, term1, sig);
  k_scores<<<2048, 256, 0, stream>>>(P, term1, sig, fin);
  k_softmax<<<16384, 256, 0, stream>>>(fin, probs);
  k_pv<<<256, 256, 0, stream>>>(probs, vcT, O);
  k_out<<<256, 256, 0, stream>>>(O, wT + (size_t)6 * 262144, out);
}

// Round 3
// 231.558 us; speedup vs baseline: 1.4637x; 1.4637x over previous
//
#include <hip/hip_runtime.h>
#include <math.h>

// Problem: b=2, h=8, n=1024, d=64, DIM=512. Inputs/outputs FLOAT32.
// Internal pipeline bf16 MFMA (f32 accumulate). SCALE = 1/8.

typedef __bf16 bf16x8 __attribute__((ext_vector_type(8)));
typedef float f32x4 __attribute__((ext_vector_type(4)));

#define SCALE 0.125f

__device__ __forceinline__ unsigned short f2bf(float f){
  unsigned int x = __builtin_bit_cast(unsigned int, f);
  unsigned int r = (x + 0x7fffu + ((x >> 16) & 1u)) >> 16;  // RNE
  return (unsigned short)r;
}
__device__ __forceinline__ f32x4 mfma16(bf16x8 a, bf16x8 b, f32x4 c){
  return __builtin_amdgcn_mfma_f32_16x16x32_bf16(a, b, c, 0, 0, 0);
}
__device__ __forceinline__ bf16x8 ld8(const unsigned short* p){
  return *(const bf16x8*)p;
}

// ---------------- K0a: x f32 -> bf16 ----------------------------------------
__global__ __launch_bounds__(256) void k_prep_x(
    const float* __restrict__ x, unsigned short* __restrict__ xb){
  int i = blockIdx.x * 256 + threadIdx.x;       // 262144 threads, 4 elems each
  float4 v = ((const float4*)x)[i];
  ushort4 o; o.x = f2bf(v.x); o.y = f2bf(v.y); o.z = f2bf(v.z); o.w = f2bf(v.w);
  ((ushort4*)xb)[i] = o;
}

// ---------------- K0b: transpose+convert 7 weights via LDS tiles ------------
__global__ __launch_bounds__(256) void k_prep_w(
    const float* __restrict__ w0, const float* __restrict__ w1,
    const float* __restrict__ w2, const float* __restrict__ w3,
    const float* __restrict__ w4, const float* __restrict__ w5,
    const float* __restrict__ w6, unsigned short* __restrict__ wT){
  __shared__ float lds[64 * 65];
  int bx = blockIdx.x;                          // 448 = 7 mats * 64 tiles
  int mat = bx >> 6, tile = bx & 63, tr = tile >> 3, tc = tile & 7;
  int k0 = tr * 64, c0 = tc * 64;
  const float* src;
  switch (mat){
    case 0: src = w0; break; case 1: src = w1; break; case 2: src = w2; break;
    case 3: src = w3; break; case 4: src = w4; break; case 5: src = w5; break;
    default: src = w6; break;
  }
  int t = threadIdx.x;
#pragma unroll
  for (int i = 0; i < 4; ++i){
    int r = (t >> 4) + i * 16, c4 = (t & 15) * 4;
    float4 v = *(const float4*)(src + (size_t)(k0 + r) * 512 + c0 + c4);
    lds[r * 65 + c4 + 0] = v.x; lds[r * 65 + c4 + 1] = v.y;
    lds[r * 65 + c4 + 2] = v.z; lds[r * 65 + c4 + 3] = v.w;
  }
  __syncthreads();
  unsigned short* dst = wT + (size_t)mat * 262144;
#pragma unroll
  for (int i = 0; i < 4; ++i){
    int oc = (t >> 4) + i * 16;                 // local out row (= global col)
    int kq = (t & 15) * 4;
    ushort4 o;
    o.x = f2bf(lds[(kq + 0) * 65 + oc]);
    o.y = f2bf(lds[(kq + 1) * 65 + oc]);
    o.z = f2bf(lds[(kq + 2) * 65 + oc]);
    o.w = f2bf(lds[(kq + 3) * 65 + oc]);
    *(ushort4*)(dst + (size_t)(c0 + oc) * 512 + k0 + kq) = o;
  }
}

// ---------------- K1: 6 projections  P[t][bh][n][d] = x @ w_t  --------------
__global__ __launch_bounds__(256) void k_proj(
    const unsigned short* __restrict__ xb, const unsigned short* __restrict__ wT,
    unsigned short* __restrict__ P, unsigned short* __restrict__ vcT){
  int gw = (blockIdx.x * 256 + threadIdx.x) >> 6;     // 6144 waves
  int lane = threadIdx.x & 63, l16 = lane & 15, quad = lane >> 4;
  int nt = gw & 7, mt = (gw >> 3) & 127, t = gw >> 10;
  int m0 = mt * 16, n0 = nt * 64;
  const unsigned short* Bt = wT + (size_t)t * 262144;
  f32x4 acc[4] = {};
  for (int k0 = 0; k0 < 512; k0 += 32){
    bf16x8 a = ld8(xb + (size_t)(m0 + l16) * 512 + k0 + quad * 8);
#pragma unroll
    for (int f = 0; f < 4; ++f){
      bf16x8 b = ld8(Bt + (size_t)(n0 + f*16 + l16) * 512 + k0 + quad * 8);
      acc[f] = mfma16(a, b, acc[f]);
    }
  }
#pragma unroll
  for (int f = 0; f < 4; ++f){
    int col = n0 + f*16 + l16;
    int h = col >> 6, d = col & 63;
#pragma unroll
    for (int r = 0; r < 4; ++r){
      int row = m0 + quad*4 + r;
      int b_ = row >> 10, n_ = row & 1023;
      int bh = b_*8 + h;
      unsigned short v = f2bf(acc[f][r]);
      P[(size_t)(t*16 + bh) * 65536 + (size_t)n_ * 64 + d] = v;
      if (t == 5) vcT[(size_t)bh * 65536 + (size_t)d * 1024 + n_] = v;  // v_c^T
    }
  }
}

// ---------------- K2: term1 (lower band) and sig (upper band) ---------------
// Only tiles k_scores will read: term1 col-block<=row-block; sig mirrored.
// wave = 16 x 64 tile, K=64. 18432 waves total.
__global__ __launch_bounds__(256) void k_qk(
    const unsigned short* __restrict__ P,
    unsigned short* __restrict__ term1, unsigned short* __restrict__ sig){
  int gw = (blockIdx.x * 256 + threadIdx.x) >> 6;     // 0..18431
  int lane = threadIdx.x & 63, l16 = lane & 15, quad = lane >> 4;
  int bhm = gw / 576;
  int idx = gw - bhm * 576;
  int bh = bhm >> 1, mat = bhm & 1;
  int B = 0;
  while (idx >= 8 * (B + 1) * (B + 2)) ++B;           // block-row 0..7
  int r2 = idx - 8 * B * (B + 1);
  int per = 2 * (B + 1);
  int mt_in = r2 / per, sub = r2 - mt_in * per;
  int m0 = (B * 8 + mt_in) * 16, n0 = sub * 64;
  if (mat){ m0 = 1008 - m0; n0 = 960 - n0; }          // mirror for sig
  unsigned short* out = (mat ? sig : term1) + (size_t)bh * 1048576;
  bool zero_tile = mat ? (n0 + 63 <= m0) : (n0 > m0 + 15);
  if (zero_tile){
#pragma unroll
    for (int f = 0; f < 4; ++f){
      int col = n0 + f*16 + l16;
#pragma unroll
      for (int r = 0; r < 4; ++r)
        out[(size_t)(m0 + quad*4 + r) * 1024 + col] = 0;
    }
    return;
  }
  const unsigned short* A  = P + (size_t)((mat ? 0 : 3)*16 + bh) * 65536;
  const unsigned short* Bt = P + (size_t)((mat ? 1 : 2)*16 + bh) * 65536;
  f32x4 acc[4] = {};
  for (int k0 = 0; k0 < 64; k0 += 32){
    bf16x8 a = ld8(A + (size_t)(m0 + l16) * 64 + k0 + quad * 8);
#pragma unroll
    for (int f = 0; f < 4; ++f){
      bf16x8 b = ld8(Bt + (size_t)(n0 + f*16 + l16) * 64 + k0 + quad * 8);
      acc[f] = mfma16(a, b, acc[f]);
    }
  }
#pragma unroll
  for (int f = 0; f < 4; ++f){
    int col = n0 + f*16 + l16;
#pragma unroll
    for (int r = 0; r < 4; ++r){
      int row = m0 + quad*4 + r;
      float v = acc[f][r] * SCALE;
      float o;
      if (mat == 0) o = (col <= row) ? v : 0.f;
      else          o = (col >  row) ? 1.f / (1.f + expf(-v)) : 0.f;
      out[(size_t)row * 1024 + col] = f2bf(o);
    }
  }
}

// ---------------- K3: fin = S_c_masked - silu(S_u)  (f32, lower tiles only) -
// Block = 128x128 tile (2x2 waves of 64x64), LDS-staged, triangular K-range.
// 576 blocks: 36 lower-tri tiles (heavy first) x 16 bh.
__global__ __launch_bounds__(256) void k_scores(
    const unsigned short* __restrict__ P, const unsigned short* __restrict__ term1,
    const unsigned short* __restrict__ sig, float* __restrict__ fin){
  __shared__ unsigned short sA[128 * 32], sB[128 * 32];
  int t = threadIdx.x;
  int bh = blockIdx.x & 15, tt = blockIdx.x >> 4;
  // decode tt -> (ti,tj), descending delta: sizes 1,2,...,8
  int k = 1, T = 0;
  while (tt >= T + k){ T += k; ++k; }
  int delta = 8 - k;
  int tj = tt - T, ti = tj + delta;
  int M0 = ti * 128, N0 = tj * 128;
  size_t sbase = (size_t)bh * 1048576;
  int lane = t & 63, l16 = lane & 15, quad = lane >> 4;
  int wid = t >> 6, wm = wid >> 1, wn = wid & 1;
  f32x4 acc_u[4][4] = {};
  f32x4 acc_c[4][4] = {};
  const unsigned short* A = term1 + sbase;
  const unsigned short* B = sig + sbase;
  int steps = (delta + 1) * 4;
  for (int s = 0; s < steps; ++s){
    int j0 = N0 + s * 32;
#pragma unroll
    for (int i = 0; i < 2; ++i){
      int L = i * 2048 + t * 8, r = L >> 5, c = L & 31;
      *(bf16x8*)(sA + L) = ld8(A + (size_t)(M0 + r) * 1024 + j0 + c);
      *(bf16x8*)(sB + L) = ld8(B + (size_t)(N0 + r) * 1024 + j0 + c);
    }
    __syncthreads();
    bf16x8 af[4], bfr[4];
#pragma unroll
    for (int mi = 0; mi < 4; ++mi)
      af[mi] = *(const bf16x8*)(sA + (wm*64 + mi*16 + l16) * 32 + quad * 8);
#pragma unroll
    for (int fi = 0; fi < 4; ++fi)
      bfr[fi] = *(const bf16x8*)(sB + (wn*64 + fi*16 + l16) * 32 + quad * 8);
#pragma unroll
    for (int mi = 0; mi < 4; ++mi)
#pragma unroll
      for (int fi = 0; fi < 4; ++fi)
        acc_u[mi][fi] = mfma16(af[mi], bfr[fi], acc_u[mi][fi]);
    __syncthreads();
  }
  // phase 2: S_c = q_c @ k_c^T over K=64
  const unsigned short* Qc = P + (size_t)(3*16 + bh) * 65536;
  const unsigned short* Kc = P + (size_t)(4*16 + bh) * 65536;
  for (int s = 0; s < 2; ++s){
    int k0 = s * 32;
#pragma unroll
    for (int i = 0; i < 2; ++i){
      int L = i * 2048 + t * 8, r = L >> 5, c = L & 31;
      *(bf16x8*)(sA + L) = ld8(Qc + (size_t)(M0 + r) * 64 + k0 + c);
      *(bf16x8*)(sB + L) = ld8(Kc + (size_t)(N0 + r) * 64 + k0 + c);
    }
    __syncthreads();
    bf16x8 af[4], bfr[4];
#pragma unroll
    for (int mi = 0; mi < 4; ++mi)
      af[mi] = *(const bf16x8*)(sA + (wm*64 + mi*16 + l16) * 32 + quad * 8);
#pragma unroll
    for (int fi = 0; fi < 4; ++fi)
      bfr[fi] = *(const bf16x8*)(sB + (wn*64 + fi*16 + l16) * 32 + quad * 8);
#pragma unroll
    for (int mi = 0; mi < 4; ++mi)
#pragma unroll
      for (int fi = 0; fi < 4; ++fi)
        acc_c[mi][fi] = mfma16(af[mi], bfr[fi], acc_c[mi][fi]);
    __syncthreads();
  }
  // epilogue
  float* out = fin + sbase;
#pragma unroll
  for (int mi = 0; mi < 4; ++mi)
#pragma unroll
    for (int fi = 0; fi < 4; ++fi){
      int col = N0 + wn*64 + fi*16 + l16;
#pragma unroll
      for (int r = 0; r < 4; ++r){
        int row = M0 + wm*64 + mi*16 + quad*4 + r;
        float su = acc_u[mi][fi][r];
        float v = acc_c[mi][fi][r] * SCALE - su / (1.f + expf(-su));
        out[(size_t)row * 1024 + col] = (col > row) ? -INFINITY : v;
      }
    }
}

// ---------------- K4a: row softmax, one wave per row, causal mask here ------
__global__ __launch_bounds__(256) void k_softmax(
    const float* __restrict__ fin, unsigned short* __restrict__ probs){
  int w = threadIdx.x >> 6, lane = threadIdx.x & 63;
  int row = blockIdx.x * 4 + w;                 // 4096 blocks, 16384 rows
  int rloc = row & 1023;
  const float* p = fin + (size_t)row * 1024;
  float4 v[4];
  float m = -INFINITY;
#pragma unroll
  for (int i = 0; i < 4; ++i){
    float4 x = ((const float4*)p)[i * 64 + lane];
    int c0 = (i * 64 + lane) * 4;
    v[i].x = (c0 + 0 <= rloc) ? x.x : -INFINITY;
    v[i].y = (c0 + 1 <= rloc) ? x.y : -INFINITY;
    v[i].z = (c0 + 2 <= rloc) ? x.z : -INFINITY;
    v[i].w = (c0 + 3 <= rloc) ? x.w : -INFINITY;
    m = fmaxf(m, fmaxf(fmaxf(v[i].x, v[i].y), fmaxf(v[i].z, v[i].w)));
  }
#pragma unroll
  for (int off = 32; off > 0; off >>= 1) m = fmaxf(m, __shfl_xor(m, off));
  float s = 0.f;
#pragma unroll
  for (int i = 0; i < 4; ++i){
    v[i].x = expf(v[i].x - m); v[i].y = expf(v[i].y - m);
    v[i].z = expf(v[i].z - m); v[i].w = expf(v[i].w - m);
    s += v[i].x + v[i].y + v[i].z + v[i].w;
  }
#pragma unroll
  for (int off = 32; off > 0; off >>= 1) s += __shfl_xor(s, off);
  float inv = 1.f / s;
  unsigned short* q = probs + (size_t)row * 1024;
#pragma unroll
  for (int i = 0; i < 4; ++i){
    ushort4 o;
    o.x = f2bf(v[i].x * inv); o.y = f2bf(v[i].y * inv);
    o.z = f2bf(v[i].z * inv); o.w = f2bf(v[i].w * inv);
    ((ushort4*)q)[i * 64 + lane] = o;
  }
}

// ---------------- K4b: O = probs @ v_c, 4-way K-split + LDS reduce ----------
// 1024 blocks: (bh, 16-row mtile), 4 waves split triangular K.
__global__ __launch_bounds__(256) void k_pv(
    const unsigned short* __restrict__ probs, const unsigned short* __restrict__ vcT,
    unsigned short* __restrict__ O){
  __shared__ float red[4][1024];
  int t = threadIdx.x, lane = t & 63, l16 = lane & 15, quad = lane >> 4, w = t >> 6;
  int bh = blockIdx.x & 15, mt = 63 - (blockIdx.x >> 4);   // heavy tiles first
  int m0 = mt * 16;
  const unsigned short* A  = probs + (size_t)bh * 1048576;
  const unsigned short* Bt = vcT + (size_t)bh * 65536;
  int ktot = (m0 + 16 + 31) >> 5;
  int per = (ktot + 3) >> 2;
  int s0 = w * per, s1 = min(s0 + per, ktot);
  f32x4 acc[4] = {};
  for (int s = s0; s < s1; ++s){
    int k0 = s * 32;
    bf16x8 a = ld8(A + (size_t)(m0 + l16) * 1024 + k0 + quad * 8);
#pragma unroll
    for (int fi = 0; fi < 4; ++fi){
      bf16x8 b = ld8(Bt + (size_t)(fi*16 + l16) * 1024 + k0 + quad * 8);
      acc[fi] = mfma16(a, b, acc[fi]);
    }
  }
#pragma unroll
  for (int fi = 0; fi < 4; ++fi)
#pragma unroll
    for (int r = 0; r < 4; ++r)
      red[w][(quad*4 + r) * 64 + fi*16 + l16] = acc[fi][r];
  __syncthreads();
  float4 a0 = ((const float4*)red[0])[t];
  float4 a1 = ((const float4*)red[1])[t];
  float4 a2 = ((const float4*)red[2])[t];
  float4 a3 = ((const float4*)red[3])[t];
  ushort4 o;
  o.x = f2bf(a0.x + a1.x + a2.x + a3.x);
  o.y = f2bf(a0.y + a1.y + a2.y + a3.y);
  o.z = f2bf(a0.z + a1.z + a2.z + a3.z);
  o.w = f2bf(a0.w + a1.w + a2.w + a3.w);
  int e = t * 4, row = e >> 6, col = e & 63;
  *(ushort4*)(O + (size_t)bh * 65536 + (size_t)(m0 + row) * 64 + col) = o;
}

// ---------------- K5: out(f32) = O_cat @ w_out, 4-way K-split ---------------
// 1024 blocks: 128 mtiles(16) x 8 ntiles(64), 4 waves split K=512.
__global__ __launch_bounds__(256) void k_out(
    const unsigned short* __restrict__ O, const unsigned short* __restrict__ woT,
    float* __restrict__ out){
  __shared__ float red[4][1024];
  int t = threadIdx.x, lane = t & 63, l16 = lane & 15, quad = lane >> 4, w = t >> 6;
  int mt = blockIdx.x >> 3, nt = blockIdx.x & 7;
  int m0 = mt * 16, n0 = nt * 64;
  int r_ = m0 + l16, b_ = r_ >> 10, n_ = r_ & 1023;
  f32x4 acc[4] = {};
#pragma unroll
  for (int s = 0; s < 4; ++s){
    int kk = w * 128 + s * 32 + quad * 8;
    int h = kk >> 6, dd = kk & 63;
    bf16x8 a = ld8(O + (size_t)(b_*8 + h) * 65536 + (size_t)n_ * 64 + dd);
#pragma unroll
    for (int fi = 0; fi < 4; ++fi){
      bf16x8 b = ld8(woT + (size_t)(n0 + fi*16 + l16) * 512 + kk);
      acc[fi] = mfma16(a, b, acc[fi]);
    }
  }
#pragma unroll
  for (int fi = 0; fi < 4; ++fi)
#pragma unroll
    for (int r = 0; r < 4; ++r)
      red[w][(quad*4 + r) * 64 + fi*16 + l16] = acc[fi][r];
  __syncthreads();
  float4 a0 = ((const float4*)red[0])[t];
  float4 a1 = ((const float4*)red[1])[t];
  float4 a2 = ((const float4*)red[2])[t];
  float4 a3 = ((const float4*)red[3])[t];
  float4 o;
  o.x = a0.x + a1.x + a2.x + a3.x;
  o.y = a0.y + a1.y + a2.y + a3.y;
  o.z = a0.z + a1.z + a2.z + a3.z;
  o.w = a0.w + a1.w + a2.w + a3.w;
  int e = t * 4, row = e >> 6, col = e & 63;
  *(float4*)(out + (size_t)(m0 + row) * 512 + n0 + col) = o;
}

extern "C" void kernel_launch(void* const* d_in, const int* in_sizes, int n_in,
                              void* d_out, int out_size, void* d_ws, size_t ws_size,
                              hipStream_t stream){
  const float* x = (const float*)d_in[0];
  float* out = (float*)d_out;
  unsigned short* ws = (unsigned short*)d_ws;

  unsigned short* wT    = ws;                                   // 7*262144
  unsigned short* xb    = wT    + (size_t)7  * 262144;          // 1048576
  unsigned short* P     = xb    + (size_t)1048576;              // 96*65536
  unsigned short* vcT   = P     + (size_t)96 * 65536;           // 16*65536
  unsigned short* term1 = vcT   + (size_t)16 * 65536;           // 16*1048576 (reused as probs)
  unsigned short* sig   = term1 + (size_t)16 * 1048576;         // 16*1048576
  unsigned short* O     = sig   + (size_t)16 * 1048576;         // 16*65536
  float*          fin   = (float*)(O + (size_t)16 * 65536);     // 16*1048576 f32
  unsigned short* probs = term1;                                 // reuse

  k_prep_x<<<1024, 256, 0, stream>>>(x, xb);
  k_prep_w<<<448, 256, 0, stream>>>(
      (const float*)d_in[1], (const float*)d_in[2], (const float*)d_in[3],
      (const float*)d_in[4], (const float*)d_in[5], (const float*)d_in[6],
      (const float*)d_in[7], wT);
  k_proj<<<1536, 256, 0, stream>>>(xb, wT, P, vcT);
  k_qk<<<4608, 256, 0, stream>>>(P, term1, sig);
  k_scores<<<576, 256, 0, stream>>>(P, term1, sig, fin);
  k_softmax<<<4096, 256, 0, stream>>>(fin, probs);
  k_pv<<<1024, 256, 0, stream>>>(probs, vcT, O);
  k_out<<<1024, 256, 0, stream>>>(O, wT + (size_t)6 * 262144, out);
}

// Round 5
// 192.992 us; speedup vs baseline: 1.7562x; 1.1998x over previous
//
#include <hip/hip_runtime.h>
#include <math.h>

// Problem: b=2, h=8, n=1024, d=64, DIM=512. Inputs/outputs FLOAT32.
// Internal pipeline bf16 MFMA (f32 accumulate). SCALE = 1/8.

typedef __bf16 bf16x8 __attribute__((ext_vector_type(8)));
typedef float f32x4 __attribute__((ext_vector_type(4)));

#define SCALE 0.125f

// async global->LDS: lane deposits 16B at (wave-uniform base + lane*16)
#define GLL(g, l) __builtin_amdgcn_global_load_lds(                         \
    (const __attribute__((address_space(1))) void*)(g),                     \
    (__attribute__((address_space(3))) void*)(l), 16, 0, 0)

__device__ __forceinline__ unsigned short f2bf(float f){
  unsigned int x = __builtin_bit_cast(unsigned int, f);
  unsigned int r = (x + 0x7fffu + ((x >> 16) & 1u)) >> 16;  // RNE
  return (unsigned short)r;
}
__device__ __forceinline__ f32x4 mfma16(bf16x8 a, bf16x8 b, f32x4 c){
  return __builtin_amdgcn_mfma_f32_16x16x32_bf16(a, b, c, 0, 0, 0);
}
__device__ __forceinline__ bf16x8 ld8(const unsigned short* p){
  return *(const bf16x8*)p;
}

// ---------------- K0a: x f32 -> bf16 ----------------------------------------
__global__ __launch_bounds__(256) void k_prep_x(
    const float* __restrict__ x, unsigned short* __restrict__ xb){
  int i = blockIdx.x * 256 + threadIdx.x;
  float4 v = ((const float4*)x)[i];
  ushort4 o; o.x = f2bf(v.x); o.y = f2bf(v.y); o.z = f2bf(v.z); o.w = f2bf(v.w);
  ((ushort4*)xb)[i] = o;
}

// ---------------- K0b: transpose+convert 7 weights via LDS tiles ------------
__global__ __launch_bounds__(256) void k_prep_w(
    const float* __restrict__ w0, const float* __restrict__ w1,
    const float* __restrict__ w2, const float* __restrict__ w3,
    const float* __restrict__ w4, const float* __restrict__ w5,
    const float* __restrict__ w6, unsigned short* __restrict__ wT){
  __shared__ float lds[64 * 65];
  int bx = blockIdx.x;                          // 448 = 7 mats * 64 tiles
  int mat = bx >> 6, tile = bx & 63, tr = tile >> 3, tc = tile & 7;
  int k0 = tr * 64, c0 = tc * 64;
  const float* src;
  switch (mat){
    case 0: src = w0; break; case 1: src = w1; break; case 2: src = w2; break;
    case 3: src = w3; break; case 4: src = w4; break; case 5: src = w5; break;
    default: src = w6; break;
  }
  int t = threadIdx.x;
#pragma unroll
  for (int i = 0; i < 4; ++i){
    int r = (t >> 4) + i * 16, c4 = (t & 15) * 4;
    float4 v = *(const float4*)(src + (size_t)(k0 + r) * 512 + c0 + c4);
    lds[r * 65 + c4 + 0] = v.x; lds[r * 65 + c4 + 1] = v.y;
    lds[r * 65 + c4 + 2] = v.z; lds[r * 65 + c4 + 3] = v.w;
  }
  __syncthreads();
  unsigned short* dst = wT + (size_t)mat * 262144;
#pragma unroll
  for (int i = 0; i < 4; ++i){
    int oc = (t >> 4) + i * 16;
    int kq = (t & 15) * 4;
    ushort4 o;
    o.x = f2bf(lds[(kq + 0) * 65 + oc]);
    o.y = f2bf(lds[(kq + 1) * 65 + oc]);
    o.z = f2bf(lds[(kq + 2) * 65 + oc]);
    o.w = f2bf(lds[(kq + 3) * 65 + oc]);
    *(ushort4*)(dst + (size_t)(c0 + oc) * 512 + k0 + kq) = o;
  }
}

// ---------------- K1: fused projections: [2048,512] @ [512,3072] ------------
// m97-style 128x128 tile, BK=32, global_load_lds staging, swapped-operand
// epilogue (4 consecutive out-cols per lane -> ushort4 stores into P layout).
__global__ __launch_bounds__(256) void k_proj(
    const unsigned short* __restrict__ xb, const unsigned short* __restrict__ wT,
    unsigned short* __restrict__ P){
  __shared__ unsigned short sA[128 * 32], sB[128 * 32];
  int t = threadIdx.x, lane = t & 63, l16 = lane & 15, quad = lane >> 4;
  int w = t >> 6, wm = w >> 1, wn = w & 1;
  int bx = blockIdx.x;                       // 384 = 16 Mtiles * 24 Ntiles
  int mt = bx / 24, nt = bx - mt * 24;
  int M0 = mt * 128, N0 = nt * 128;
  int matb = N0 >> 9;                        // weight matrix (block-uniform)
  int nin = N0 & 511;                        // col within that matrix
  int srow = (lane >> 2), scol = (lane & 3) * 8;
  const unsigned short* gA = xb + (size_t)(M0 + w*32 + srow) * 512 + scol;
  const unsigned short* gB = wT + (size_t)matb * 262144
                               + (size_t)(nin + w*32 + srow) * 512 + scol;
  unsigned short* lA = sA + (w*32) * 32;
  unsigned short* lB = sB + (w*32) * 32;
  f32x4 acc[4][4] = {};                      // [fi=wcol grp][mi=xrow grp]
  for (int k0 = 0; k0 < 512; k0 += 32){
    GLL(gA + k0,            lA);
    GLL(gA + k0 + 16*512,   lA + 16*32);
    GLL(gB + k0,            lB);
    GLL(gB + k0 + 16*512,   lB + 16*32);
    __syncthreads();
    bf16x8 aw[4], ax[4];
#pragma unroll
    for (int fi = 0; fi < 4; ++fi)
      aw[fi] = *(const bf16x8*)(sB + (wn*64 + fi*16 + l16) * 32 + quad * 8);
#pragma unroll
    for (int mi = 0; mi < 4; ++mi)
      ax[mi] = *(const bf16x8*)(sA + (wm*64 + mi*16 + l16) * 32 + quad * 8);
#pragma unroll
    for (int fi = 0; fi < 4; ++fi)
#pragma unroll
      for (int mi = 0; mi < 4; ++mi)
        acc[fi][mi] = mfma16(aw[fi], ax[mi], acc[fi][mi]);
    __syncthreads();
  }
#pragma unroll
  for (int fi = 0; fi < 4; ++fi)
#pragma unroll
    for (int mi = 0; mi < 4; ++mi){
      int row = M0 + wm*64 + mi*16 + l16;       // x-row
      int b_ = row >> 10, n_ = row & 1023;
      int c0 = N0 + wn*64 + fi*16 + quad*4;     // out col (mult of 4)
      int h = (c0 & 511) >> 6, d = c0 & 63;
      int bh = b_*8 + h;
      ushort4 o;
      o.x = f2bf(acc[fi][mi][0]); o.y = f2bf(acc[fi][mi][1]);
      o.z = f2bf(acc[fi][mi][2]); o.w = f2bf(acc[fi][mi][3]);
      *(ushort4*)(P + (size_t)(matb*16 + bh) * 65536 + (size_t)n_ * 64 + d) = o;
    }
}

// ---------------- K1b: vcT[bh][d][n] = P5[bh][n][d] transpose ---------------
__global__ __launch_bounds__(256) void k_vct(
    const unsigned short* __restrict__ P5, unsigned short* __restrict__ vcT){
  __shared__ unsigned short lds[64 * 72];
  int bh = blockIdx.x >> 4, nt = blockIdx.x & 15;   // 256 blocks
  int N0 = nt * 64;
  const unsigned short* src = P5 + (size_t)bh * 65536 + (size_t)N0 * 64;
  int t = threadIdx.x;
#pragma unroll
  for (int it = 0; it < 2; ++it){
    int id = it * 256 + t;
    int r = id >> 3, c8 = (id & 7) * 8;
    ushort4 v0 = *(const ushort4*)(src + r * 64 + c8);
    ushort4 v1 = *(const ushort4*)(src + r * 64 + c8 + 4);
    *(ushort4*)(lds + r * 72 + c8) = v0;
    *(ushort4*)(lds + r * 72 + c8 + 4) = v1;
  }
  __syncthreads();
  unsigned short* dst = vcT + (size_t)bh * 65536;
#pragma unroll
  for (int it = 0; it < 2; ++it){
    int id = it * 256 + t;
    int dd = id >> 3, n8 = (id & 7) * 8;
    ushort4 a, b;
    a.x = lds[(n8+0)*72 + dd]; a.y = lds[(n8+1)*72 + dd];
    a.z = lds[(n8+2)*72 + dd]; a.w = lds[(n8+3)*72 + dd];
    b.x = lds[(n8+4)*72 + dd]; b.y = lds[(n8+5)*72 + dd];
    b.z = lds[(n8+6)*72 + dd]; b.w = lds[(n8+7)*72 + dd];
    *(ushort4*)(dst + (size_t)dd * 1024 + N0 + n8) = a;
    *(ushort4*)(dst + (size_t)dd * 1024 + N0 + n8 + 4) = b;
  }
}

// ---------------- K2: term1 (lower band) and sig (upper band) ---------------
// Swapped operands: per-lane 4 consecutive cols -> ushort4 stores.
__global__ __launch_bounds__(256) void k_qk(
    const unsigned short* __restrict__ P,
    unsigned short* __restrict__ term1, unsigned short* __restrict__ sig){
  int gw = (blockIdx.x * 256 + threadIdx.x) >> 6;     // 0..18431
  int lane = threadIdx.x & 63, l16 = lane & 15, quad = lane >> 4;
  int bhm = gw / 576;
  int idx = gw - bhm * 576;
  int bh = bhm >> 1, mat = bhm & 1;
  int B = 0;
  while (idx >= 8 * (B + 1) * (B + 2)) ++B;
  int r2 = idx - 8 * B * (B + 1);
  int per = 2 * (B + 1);
  int mt_in = r2 / per, sub = r2 - mt_in * per;
  int m0 = (B * 8 + mt_in) * 16, n0 = sub * 64;
  if (mat){ m0 = 1008 - m0; n0 = 960 - n0; }
  unsigned short* out = (mat ? sig : term1) + (size_t)bh * 1048576;
  int row = m0 + l16;
  bool zero_tile = mat ? (n0 + 63 <= m0) : (n0 > m0 + 15);
  if (zero_tile){
    ushort4 z = {0, 0, 0, 0};
#pragma unroll
    for (int f = 0; f < 4; ++f)
      *(ushort4*)(out + (size_t)row * 1024 + n0 + f*16 + quad*4) = z;
    return;
  }
  const unsigned short* A  = P + (size_t)((mat ? 0 : 3)*16 + bh) * 65536;
  const unsigned short* Bt = P + (size_t)((mat ? 1 : 2)*16 + bh) * 65536;
  f32x4 acc[4] = {};
  for (int k0 = 0; k0 < 64; k0 += 32){
    bf16x8 bi = ld8(A + (size_t)(m0 + l16) * 64 + k0 + quad * 8);   // i-rows (B-op)
#pragma unroll
    for (int f = 0; f < 4; ++f){
      bf16x8 aj = ld8(Bt + (size_t)(n0 + f*16 + l16) * 64 + k0 + quad * 8);
      acc[f] = mfma16(aj, bi, acc[f]);
    }
  }
#pragma unroll
  for (int f = 0; f < 4; ++f){
    int c0 = n0 + f*16 + quad*4;
    ushort4 o;
#pragma unroll
    for (int r = 0; r < 4; ++r){
      int col = c0 + r;
      float v = acc[f][r] * SCALE;
      unsigned short res;
      if (mat == 0) res = (col <= row) ? f2bf(v) : (unsigned short)0;
      else          res = (col >  row) ? f2bf(1.f / (1.f + expf(-v))) : (unsigned short)0;
      ((unsigned short*)&o)[r] = res;
    }
    *(ushort4*)(out + (size_t)row * 1024 + c0) = o;
  }
}

// ---------------- K3: fin = S_c_masked - silu(S_u)  (f32, lower tiles only) -
// 128x128 tile, GLL staging, swapped operands (float4 stores).
__global__ __launch_bounds__(256) void k_scores(
    const unsigned short* __restrict__ P, const unsigned short* __restrict__ term1,
    const unsigned short* __restrict__ sig, float* __restrict__ fin){
  __shared__ unsigned short sA[128 * 32], sB[128 * 32];
  int t = threadIdx.x;
  int bh = blockIdx.x & 15, tt = blockIdx.x >> 4;
  int k = 1, T = 0;
  while (tt >= T + k){ T += k; ++k; }
  int delta = 8 - k;
  int tj = tt - T, ti = tj + delta;
  int M0 = ti * 128, N0 = tj * 128;
  size_t sbase = (size_t)bh * 1048576;
  int lane = t & 63, l16 = lane & 15, quad = lane >> 4;
  int w = t >> 6, wm = w >> 1, wn = w & 1;
  int srow = (lane >> 2), scol = (lane & 3) * 8;
  unsigned short* lA = sA + (w*32) * 32;
  unsigned short* lB = sB + (w*32) * 32;
  f32x4 acc_u[4][4] = {};            // [fi=col grp (k)][mi=row grp (i)]
  f32x4 acc_c[4][4] = {};
  {
    const unsigned short* gA = term1 + sbase + (size_t)(M0 + w*32 + srow) * 1024 + scol;
    const unsigned short* gB = sig   + sbase + (size_t)(N0 + w*32 + srow) * 1024 + scol;
    int steps = (delta + 1) * 4;
    for (int s = 0; s < steps; ++s){
      int j0 = N0 + s * 32;                  // FIX (R4 bug): j starts at N0
      GLL(gA + j0,             lA);
      GLL(gA + j0 + 16*1024,   lA + 16*32);
      GLL(gB + j0,             lB);
      GLL(gB + j0 + 16*1024,   lB + 16*32);
      __syncthreads();
      bf16x8 af[4], bfr[4];
#pragma unroll
      for (int mi = 0; mi < 4; ++mi)
        af[mi] = *(const bf16x8*)(sA + (wm*64 + mi*16 + l16) * 32 + quad * 8);
#pragma unroll
      for (int fi = 0; fi < 4; ++fi)
        bfr[fi] = *(const bf16x8*)(sB + (wn*64 + fi*16 + l16) * 32 + quad * 8);
#pragma unroll
      for (int fi = 0; fi < 4; ++fi)
#pragma unroll
        for (int mi = 0; mi < 4; ++mi)
          acc_u[fi][mi] = mfma16(bfr[fi], af[mi], acc_u[fi][mi]);
      __syncthreads();
    }
  }
  {
    const unsigned short* Qc = P + (size_t)(3*16 + bh) * 65536;
    const unsigned short* Kc = P + (size_t)(4*16 + bh) * 65536;
    const unsigned short* gA = Qc + (size_t)(M0 + w*32 + srow) * 64 + scol;
    const unsigned short* gB = Kc + (size_t)(N0 + w*32 + srow) * 64 + scol;
    for (int s = 0; s < 2; ++s){
      int k0 = s * 32;
      GLL(gA + k0,           lA);
      GLL(gA + k0 + 16*64,   lA + 16*32);
      GLL(gB + k0,           lB);
      GLL(gB + k0 + 16*64,   lB + 16*32);
      __syncthreads();
      bf16x8 af[4], bfr[4];
#pragma unroll
      for (int mi = 0; mi < 4; ++mi)
        af[mi] = *(const bf16x8*)(sA + (wm*64 + mi*16 + l16) * 32 + quad * 8);
#pragma unroll
      for (int fi = 0; fi < 4; ++fi)
        bfr[fi] = *(const bf16x8*)(sB + (wn*64 + fi*16 + l16) * 32 + quad * 8);
#pragma unroll
      for (int fi = 0; fi < 4; ++fi)
#pragma unroll
        for (int mi = 0; mi < 4; ++mi)
          acc_c[fi][mi] = mfma16(bfr[fi], af[mi], acc_c[fi][mi]);
      __syncthreads();
    }
  }
  float* out = fin + sbase;
#pragma unroll
  for (int fi = 0; fi < 4; ++fi)
#pragma unroll
    for (int mi = 0; mi < 4; ++mi){
      int row = M0 + wm*64 + mi*16 + l16;
      int c0 = N0 + wn*64 + fi*16 + quad*4;
      float4 o;
#pragma unroll
      for (int r = 0; r < 4; ++r){
        int col = c0 + r;
        float su = acc_u[fi][mi][r];
        float v = acc_c[fi][mi][r] * SCALE - su / (1.f + expf(-su));
        ((float*)&o)[r] = (col > row) ? -INFINITY : v;
      }
      *(float4*)(out + (size_t)row * 1024 + c0) = o;
    }
}

// ---------------- K4a: row softmax, one wave per row, causal mask here ------
__global__ __launch_bounds__(256) void k_softmax(
    const float* __restrict__ fin, unsigned short* __restrict__ probs){
  int w = threadIdx.x >> 6, lane = threadIdx.x & 63;
  int row = blockIdx.x * 4 + w;
  int rloc = row & 1023;
  const float* p = fin + (size_t)row * 1024;
  float4 v[4];
  float m = -INFINITY;
#pragma unroll
  for (int i = 0; i < 4; ++i){
    float4 x = ((const float4*)p)[i * 64 + lane];
    int c0 = (i * 64 + lane) * 4;
    v[i].x = (c0 + 0 <= rloc) ? x.x : -INFINITY;
    v[i].y = (c0 + 1 <= rloc) ? x.y : -INFINITY;
    v[i].z = (c0 + 2 <= rloc) ? x.z : -INFINITY;
    v[i].w = (c0 + 3 <= rloc) ? x.w : -INFINITY;
    m = fmaxf(m, fmaxf(fmaxf(v[i].x, v[i].y), fmaxf(v[i].z, v[i].w)));
  }
#pragma unroll
  for (int off = 32; off > 0; off >>= 1) m = fmaxf(m, __shfl_xor(m, off));
  float s = 0.f;
#pragma unroll
  for (int i = 0; i < 4; ++i){
    v[i].x = expf(v[i].x - m); v[i].y = expf(v[i].y - m);
    v[i].z = expf(v[i].z - m); v[i].w = expf(v[i].w - m);
    s += v[i].x + v[i].y + v[i].z + v[i].w;
  }
#pragma unroll
  for (int off = 32; off > 0; off >>= 1) s += __shfl_xor(s, off);
  float inv = 1.f / s;
  unsigned short* q = probs + (size_t)row * 1024;
#pragma unroll
  for (int i = 0; i < 4; ++i){
    ushort4 o;
    o.x = f2bf(v[i].x * inv); o.y = f2bf(v[i].y * inv);
    o.z = f2bf(v[i].z * inv); o.w = f2bf(v[i].w * inv);
    ((ushort4*)q)[i * 64 + lane] = o;
  }
}

// ---------------- K4b: O = probs @ v_c, 4-way K-split + LDS reduce ----------
__global__ __launch_bounds__(256) void k_pv(
    const unsigned short* __restrict__ probs, const unsigned short* __restrict__ vcT,
    unsigned short* __restrict__ O){
  __shared__ float red[4][1024];
  int t = threadIdx.x, lane = t & 63, l16 = lane & 15, quad = lane >> 4, w = t >> 6;
  int bh = blockIdx.x & 15, mt = 63 - (blockIdx.x >> 4);
  int m0 = mt * 16;
  const unsigned short* A  = probs + (size_t)bh * 1048576;
  const unsigned short* Bt = vcT + (size_t)bh * 65536;
  int ktot = (m0 + 16 + 31) >> 5;
  int per = (ktot + 3) >> 2;
  int s0 = w * per, s1 = min(s0 + per, ktot);
  f32x4 acc[4] = {};
  for (int s = s0; s < s1; ++s){
    int k0 = s * 32;
    bf16x8 a = ld8(A + (size_t)(m0 + l16) * 1024 + k0 + quad * 8);
#pragma unroll
    for (int fi = 0; fi < 4; ++fi){
      bf16x8 b = ld8(Bt + (size_t)(fi*16 + l16) * 1024 + k0 + quad * 8);
      acc[fi] = mfma16(a, b, acc[fi]);
    }
  }
#pragma unroll
  for (int fi = 0; fi < 4; ++fi)
#pragma unroll
    for (int r = 0; r < 4; ++r)
      red[w][(quad*4 + r) * 64 + fi*16 + l16] = acc[fi][r];
  __syncthreads();
  float4 a0 = ((const float4*)red[0])[t];
  float4 a1 = ((const float4*)red[1])[t];
  float4 a2 = ((const float4*)red[2])[t];
  float4 a3 = ((const float4*)red[3])[t];
  ushort4 o;
  o.x = f2bf(a0.x + a1.x + a2.x + a3.x);
  o.y = f2bf(a0.y + a1.y + a2.y + a3.y);
  o.z = f2bf(a0.z + a1.z + a2.z + a3.z);
  o.w = f2bf(a0.w + a1.w + a2.w + a3.w);
  int e = t * 4, row = e >> 6, col = e & 63;
  *(ushort4*)(O + (size_t)bh * 65536 + (size_t)(m0 + row) * 64 + col) = o;
}

// ---------------- K5: out(f32) = O_cat @ w_out, 4-way K-split ---------------
__global__ __launch_bounds__(256) void k_out(
    const unsigned short* __restrict__ O, const unsigned short* __restrict__ woT,
    float* __restrict__ out){
  __shared__ float red[4][1024];
  int t = threadIdx.x, lane = t & 63, l16 = lane & 15, quad = lane >> 4, w = t >> 6;
  int mt = blockIdx.x >> 3, nt = blockIdx.x & 7;
  int m0 = mt * 16, n0 = nt * 64;
  int r_ = m0 + l16, b_ = r_ >> 10, n_ = r_ & 1023;
  f32x4 acc[4] = {};
#pragma unroll
  for (int s = 0; s < 4; ++s){
    int kk = w * 128 + s * 32 + quad * 8;
    int h = kk >> 6, dd = kk & 63;
    bf16x8 a = ld8(O + (size_t)(b_*8 + h) * 65536 + (size_t)n_ * 64 + dd);
#pragma unroll
    for (int fi = 0; fi < 4; ++fi){
      bf16x8 b = ld8(woT + (size_t)(n0 + fi*16 + l16) * 512 + kk);
      acc[fi] = mfma16(a, b, acc[fi]);
    }
  }
#pragma unroll
  for (int fi = 0; fi < 4; ++fi)
#pragma unroll
    for (int r = 0; r < 4; ++r)
      red[w][(quad*4 + r) * 64 + fi*16 + l16] = acc[fi][r];
  __syncthreads();
  float4 a0 = ((const float4*)red[0])[t];
  float4 a1 = ((const float4*)red[1])[t];
  float4 a2 = ((const float4*)red[2])[t];
  float4 a3 = ((const float4*)red[3])[t];
  float4 o;
  o.x = a0.x + a1.x + a2.x + a3.x;
  o.y = a0.y + a1.y + a2.y + a3.y;
  o.z = a0.z + a1.z + a2.z + a3.z;
  o.w = a0.w + a1.w + a2.w + a3.w;
  int e = t * 4, row = e >> 6, col = e & 63;
  *(float4*)(out + (size_t)(m0 + row) * 512 + n0 + col) = o;
}

extern "C" void kernel_launch(void* const* d_in, const int* in_sizes, int n_in,
                              void* d_out, int out_size, void* d_ws, size_t ws_size,
                              hipStream_t stream){
  const float* x = (const float*)d_in[0];
  float* out = (float*)d_out;
  unsigned short* ws = (unsigned short*)d_ws;

  unsigned short* wT    = ws;                                   // 7*262144
  unsigned short* xb    = wT    + (size_t)7  * 262144;          // 1048576
  unsigned short* P     = xb    + (size_t)1048576;              // 96*65536
  unsigned short* vcT   = P     + (size_t)96 * 65536;           // 16*65536
  unsigned short* term1 = vcT   + (size_t)16 * 65536;           // 16*1048576 (reused as probs)
  unsigned short* sig   = term1 + (size_t)16 * 1048576;         // 16*1048576
  unsigned short* O     = sig   + (size_t)16 * 1048576;         // 16*65536
  float*          fin   = (float*)(O + (size_t)16 * 65536);     // 16*1048576 f32
  unsigned short* probs = term1;                                 // reuse

  k_prep_x<<<1024, 256, 0, stream>>>(x, xb);
  k_prep_w<<<448, 256, 0, stream>>>(
      (const float*)d_in[1], (const float*)d_in[2], (const float*)d_in[3],
      (const float*)d_in[4], (const float*)d_in[5], (const float*)d_in[6],
      (const float*)d_in[7], wT);
  k_proj<<<384, 256, 0, stream>>>(xb, wT, P);
  k_vct<<<256, 256, 0, stream>>>(P + (size_t)5*16*65536, vcT);
  k_qk<<<4608, 256, 0, stream>>>(P, term1, sig);
  k_scores<<<576, 256, 0, stream>>>(P, term1, sig, fin);
  k_softmax<<<4096, 256, 0, stream>>>(fin, probs);
  k_pv<<<1024, 256, 0, stream>>>(probs, vcT, O);
  k_out<<<1024, 256, 0, stream>>>(O, wT + (size_t)6 * 262144, out);
}

// Round 6
// 180.598 us; speedup vs baseline: 1.8767x; 1.0686x over previous
//
#include <hip/hip_runtime.h>
#include <math.h>

// Problem: b=2, h=8, n=1024, d=64, DIM=512. Inputs/outputs FLOAT32.
// Internal pipeline bf16 MFMA (f32 accumulate). SCALE = 1/8.

typedef __bf16 bf16x8 __attribute__((ext_vector_type(8)));
typedef float f32x4 __attribute__((ext_vector_type(4)));

#define SCALE 0.125f

// async global->LDS: lane deposits 16B at (wave-uniform base + lane*16)
#define GLL(g, l) __builtin_amdgcn_global_load_lds(                         \
    (const __attribute__((address_space(1))) void*)(g),                     \
    (__attribute__((address_space(3))) void*)(l), 16, 0, 0)

__device__ __forceinline__ unsigned short f2bf(float f){
  unsigned int x = __builtin_bit_cast(unsigned int, f);
  unsigned int r = (x + 0x7fffu + ((x >> 16) & 1u)) >> 16;  // RNE
  return (unsigned short)r;
}
__device__ __forceinline__ f32x4 mfma16(bf16x8 a, bf16x8 b, f32x4 c){
  return __builtin_amdgcn_mfma_f32_16x16x32_bf16(a, b, c, 0, 0, 0);
}
__device__ __forceinline__ bf16x8 ld8(const unsigned short* p){
  return *(const bf16x8*)p;
}

// ---------------- K0: x f32->bf16 (blocks 0..1023) + weight transpose -------
__global__ __launch_bounds__(256) void k_prep(
    const float* __restrict__ x,
    const float* __restrict__ w0, const float* __restrict__ w1,
    const float* __restrict__ w2, const float* __restrict__ w3,
    const float* __restrict__ w4, const float* __restrict__ w5,
    const float* __restrict__ w6,
    unsigned short* __restrict__ xb, unsigned short* __restrict__ wT){
  int t = threadIdx.x;
  if (blockIdx.x < 1024){
    int i = blockIdx.x * 256 + t;
    float4 v = ((const float4*)x)[i];
    ushort4 o; o.x = f2bf(v.x); o.y = f2bf(v.y); o.z = f2bf(v.z); o.w = f2bf(v.w);
    ((ushort4*)xb)[i] = o;
    return;
  }
  __shared__ float lds[64 * 65];
  int bx = blockIdx.x - 1024;                   // 448 = 7 mats * 64 tiles
  int mat = bx >> 6, tile = bx & 63, tr = tile >> 3, tc = tile & 7;
  int k0 = tr * 64, c0 = tc * 64;
  const float* src;
  switch (mat){
    case 0: src = w0; break; case 1: src = w1; break; case 2: src = w2; break;
    case 3: src = w3; break; case 4: src = w4; break; case 5: src = w5; break;
    default: src = w6; break;
  }
#pragma unroll
  for (int i = 0; i < 4; ++i){
    int r = (t >> 4) + i * 16, c4 = (t & 15) * 4;
    float4 v = *(const float4*)(src + (size_t)(k0 + r) * 512 + c0 + c4);
    lds[r * 65 + c4 + 0] = v.x; lds[r * 65 + c4 + 1] = v.y;
    lds[r * 65 + c4 + 2] = v.z; lds[r * 65 + c4 + 3] = v.w;
  }
  __syncthreads();
  unsigned short* dst = wT + (size_t)mat * 262144;
#pragma unroll
  for (int i = 0; i < 4; ++i){
    int oc = (t >> 4) + i * 16;
    int kq = (t & 15) * 4;
    ushort4 o;
    o.x = f2bf(lds[(kq + 0) * 65 + oc]);
    o.y = f2bf(lds[(kq + 1) * 65 + oc]);
    o.z = f2bf(lds[(kq + 2) * 65 + oc]);
    o.w = f2bf(lds[(kq + 3) * 65 + oc]);
    *(ushort4*)(dst + (size_t)(c0 + oc) * 512 + k0 + kq) = o;
  }
}

// ---------------- K1: fused projections: [2048,512] @ [512,3072] ------------
__global__ __launch_bounds__(256) void k_proj(
    const unsigned short* __restrict__ xb, const unsigned short* __restrict__ wT,
    unsigned short* __restrict__ P){
  __shared__ unsigned short sA[128 * 32], sB[128 * 32];
  int t = threadIdx.x, lane = t & 63, l16 = lane & 15, quad = lane >> 4;
  int w = t >> 6, wm = w >> 1, wn = w & 1;
  int bx = blockIdx.x;                       // 384 = 16 Mtiles * 24 Ntiles
  int mt = bx / 24, nt = bx - mt * 24;
  int M0 = mt * 128, N0 = nt * 128;
  int matb = N0 >> 9;
  int nin = N0 & 511;
  int srow = (lane >> 2), scol = (lane & 3) * 8;
  const unsigned short* gA = xb + (size_t)(M0 + w*32 + srow) * 512 + scol;
  const unsigned short* gB = wT + (size_t)matb * 262144
                               + (size_t)(nin + w*32 + srow) * 512 + scol;
  unsigned short* lA = sA + (w*32) * 32;
  unsigned short* lB = sB + (w*32) * 32;
  f32x4 acc[4][4] = {};
  for (int k0 = 0; k0 < 512; k0 += 32){
    GLL(gA + k0,            lA);
    GLL(gA + k0 + 16*512,   lA + 16*32);
    GLL(gB + k0,            lB);
    GLL(gB + k0 + 16*512,   lB + 16*32);
    __syncthreads();
    bf16x8 aw[4], ax[4];
#pragma unroll
    for (int fi = 0; fi < 4; ++fi)
      aw[fi] = *(const bf16x8*)(sB + (wn*64 + fi*16 + l16) * 32 + quad * 8);
#pragma unroll
    for (int mi = 0; mi < 4; ++mi)
      ax[mi] = *(const bf16x8*)(sA + (wm*64 + mi*16 + l16) * 32 + quad * 8);
#pragma unroll
    for (int fi = 0; fi < 4; ++fi)
#pragma unroll
      for (int mi = 0; mi < 4; ++mi)
        acc[fi][mi] = mfma16(aw[fi], ax[mi], acc[fi][mi]);
    __syncthreads();
  }
#pragma unroll
  for (int fi = 0; fi < 4; ++fi)
#pragma unroll
    for (int mi = 0; mi < 4; ++mi){
      int row = M0 + wm*64 + mi*16 + l16;
      int b_ = row >> 10, n_ = row & 1023;
      int c0 = N0 + wn*64 + fi*16 + quad*4;
      int h = (c0 & 511) >> 6, d = c0 & 63;
      int bh = b_*8 + h;
      ushort4 o;
      o.x = f2bf(acc[fi][mi][0]); o.y = f2bf(acc[fi][mi][1]);
      o.z = f2bf(acc[fi][mi][2]); o.w = f2bf(acc[fi][mi][3]);
      *(ushort4*)(P + (size_t)(matb*16 + bh) * 65536 + (size_t)n_ * 64 + d) = o;
    }
}

// ---------------- K1b: vcT[bh][d][n] = P5[bh][n][d] transpose ---------------
__global__ __launch_bounds__(256) void k_vct(
    const unsigned short* __restrict__ P5, unsigned short* __restrict__ vcT){
  __shared__ unsigned short lds[64 * 72];
  int bh = blockIdx.x >> 4, nt = blockIdx.x & 15;   // 256 blocks
  int N0 = nt * 64;
  const unsigned short* src = P5 + (size_t)bh * 65536 + (size_t)N0 * 64;
  int t = threadIdx.x;
#pragma unroll
  for (int it = 0; it < 2; ++it){
    int id = it * 256 + t;
    int r = id >> 3, c8 = (id & 7) * 8;
    ushort4 v0 = *(const ushort4*)(src + r * 64 + c8);
    ushort4 v1 = *(const ushort4*)(src + r * 64 + c8 + 4);
    *(ushort4*)(lds + r * 72 + c8) = v0;
    *(ushort4*)(lds + r * 72 + c8 + 4) = v1;
  }
  __syncthreads();
  unsigned short* dst = vcT + (size_t)bh * 65536;
#pragma unroll
  for (int it = 0; it < 2; ++it){
    int id = it * 256 + t;
    int dd = id >> 3, n8 = (id & 7) * 8;
    ushort4 a, b;
    a.x = lds[(n8+0)*72 + dd]; a.y = lds[(n8+1)*72 + dd];
    a.z = lds[(n8+2)*72 + dd]; a.w = lds[(n8+3)*72 + dd];
    b.x = lds[(n8+4)*72 + dd]; b.y = lds[(n8+5)*72 + dd];
    b.z = lds[(n8+6)*72 + dd]; b.w = lds[(n8+7)*72 + dd];
    *(ushort4*)(dst + (size_t)dd * 1024 + N0 + n8) = a;
    *(ushort4*)(dst + (size_t)dd * 1024 + N0 + n8 + 4) = b;
  }
}

// ---------------- K2: term1 (lower band) and sig (upper band) ---------------
__global__ __launch_bounds__(256) void k_qk(
    const unsigned short* __restrict__ P,
    unsigned short* __restrict__ term1, unsigned short* __restrict__ sig){
  int gw = (blockIdx.x * 256 + threadIdx.x) >> 6;     // 0..18431
  int lane = threadIdx.x & 63, l16 = lane & 15, quad = lane >> 4;
  int bhm = gw / 576;
  int idx = gw - bhm * 576;
  int bh = bhm >> 1, mat = bhm & 1;
  int B = 0;
  while (idx >= 8 * (B + 1) * (B + 2)) ++B;
  int r2 = idx - 8 * B * (B + 1);
  int per = 2 * (B + 1);
  int mt_in = r2 / per, sub = r2 - mt_in * per;
  int m0 = (B * 8 + mt_in) * 16, n0 = sub * 64;
  if (mat){ m0 = 1008 - m0; n0 = 960 - n0; }
  unsigned short* out = (mat ? sig : term1) + (size_t)bh * 1048576;
  int row = m0 + l16;
  bool zero_tile = mat ? (n0 + 63 <= m0) : (n0 > m0 + 15);
  if (zero_tile){
    ushort4 z = {0, 0, 0, 0};
#pragma unroll
    for (int f = 0; f < 4; ++f)
      *(ushort4*)(out + (size_t)row * 1024 + n0 + f*16 + quad*4) = z;
    return;
  }
  const unsigned short* A  = P + (size_t)((mat ? 0 : 3)*16 + bh) * 65536;
  const unsigned short* Bt = P + (size_t)((mat ? 1 : 2)*16 + bh) * 65536;
  f32x4 acc[4] = {};
  for (int k0 = 0; k0 < 64; k0 += 32){
    bf16x8 bi = ld8(A + (size_t)(m0 + l16) * 64 + k0 + quad * 8);
#pragma unroll
    for (int f = 0; f < 4; ++f){
      bf16x8 aj = ld8(Bt + (size_t)(n0 + f*16 + l16) * 64 + k0 + quad * 8);
      acc[f] = mfma16(aj, bi, acc[f]);
    }
  }
#pragma unroll
  for (int f = 0; f < 4; ++f){
    int c0 = n0 + f*16 + quad*4;
    ushort4 o;
#pragma unroll
    for (int r = 0; r < 4; ++r){
      int col = c0 + r;
      float v = acc[f][r] * SCALE;
      unsigned short res;
      if (mat == 0) res = (col <= row) ? f2bf(v) : (unsigned short)0;
      else          res = (col >  row) ? f2bf(1.f / (1.f + expf(-v))) : (unsigned short)0;
      ((unsigned short*)&o)[r] = res;
    }
    *(ushort4*)(out + (size_t)row * 1024 + c0) = o;
  }
}

// ---------------- K3: fin = S_c_masked - silu(S_u)  (f32, lower tiles only) -
__global__ __launch_bounds__(256) void k_scores(
    const unsigned short* __restrict__ P, const unsigned short* __restrict__ term1,
    const unsigned short* __restrict__ sig, float* __restrict__ fin){
  __shared__ unsigned short sA[128 * 32], sB[128 * 32];
  int t = threadIdx.x;
  int bh = blockIdx.x & 15, tt = blockIdx.x >> 4;
  int k = 1, T = 0;
  while (tt >= T + k){ T += k; ++k; }
  int delta = 8 - k;
  int tj = tt - T, ti = tj + delta;
  int M0 = ti * 128, N0 = tj * 128;
  size_t sbase = (size_t)bh * 1048576;
  int lane = t & 63, l16 = lane & 15, quad = lane >> 4;
  int w = t >> 6, wm = w >> 1, wn = w & 1;
  int srow = (lane >> 2), scol = (lane & 3) * 8;
  unsigned short* lA = sA + (w*32) * 32;
  unsigned short* lB = sB + (w*32) * 32;
  f32x4 acc_u[4][4] = {};
  f32x4 acc_c[4][4] = {};
  {
    const unsigned short* gA = term1 + sbase + (size_t)(M0 + w*32 + srow) * 1024 + scol;
    const unsigned short* gB = sig   + sbase + (size_t)(N0 + w*32 + srow) * 1024 + scol;
    int steps = (delta + 1) * 4;
    for (int s = 0; s < steps; ++s){
      int j0 = N0 + s * 32;
      GLL(gA + j0,             lA);
      GLL(gA + j0 + 16*1024,   lA + 16*32);
      GLL(gB + j0,             lB);
      GLL(gB + j0 + 16*1024,   lB + 16*32);
      __syncthreads();
      bf16x8 af[4], bfr[4];
#pragma unroll
      for (int mi = 0; mi < 4; ++mi)
        af[mi] = *(const bf16x8*)(sA + (wm*64 + mi*16 + l16) * 32 + quad * 8);
#pragma unroll
      for (int fi = 0; fi < 4; ++fi)
        bfr[fi] = *(const bf16x8*)(sB + (wn*64 + fi*16 + l16) * 32 + quad * 8);
#pragma unroll
      for (int fi = 0; fi < 4; ++fi)
#pragma unroll
        for (int mi = 0; mi < 4; ++mi)
          acc_u[fi][mi] = mfma16(bfr[fi], af[mi], acc_u[fi][mi]);
      __syncthreads();
    }
  }
  {
    const unsigned short* Qc = P + (size_t)(3*16 + bh) * 65536;
    const unsigned short* Kc = P + (size_t)(4*16 + bh) * 65536;
    const unsigned short* gA = Qc + (size_t)(M0 + w*32 + srow) * 64 + scol;
    const unsigned short* gB = Kc + (size_t)(N0 + w*32 + srow) * 64 + scol;
    for (int s = 0; s < 2; ++s){
      int k0 = s * 32;
      GLL(gA + k0,           lA);
      GLL(gA + k0 + 16*64,   lA + 16*32);
      GLL(gB + k0,           lB);
      GLL(gB + k0 + 16*64,   lB + 16*32);
      __syncthreads();
      bf16x8 af[4], bfr[4];
#pragma unroll
      for (int mi = 0; mi < 4; ++mi)
        af[mi] = *(const bf16x8*)(sA + (wm*64 + mi*16 + l16) * 32 + quad * 8);
#pragma unroll
      for (int fi = 0; fi < 4; ++fi)
        bfr[fi] = *(const bf16x8*)(sB + (wn*64 + fi*16 + l16) * 32 + quad * 8);
#pragma unroll
      for (int fi = 0; fi < 4; ++fi)
#pragma unroll
        for (int mi = 0; mi < 4; ++mi)
          acc_c[fi][mi] = mfma16(bfr[fi], af[mi], acc_c[fi][mi]);
      __syncthreads();
    }
  }
  float* out = fin + sbase;
#pragma unroll
  for (int fi = 0; fi < 4; ++fi)
#pragma unroll
    for (int mi = 0; mi < 4; ++mi){
      int row = M0 + wm*64 + mi*16 + l16;
      int c0 = N0 + wn*64 + fi*16 + quad*4;
      float4 o;
#pragma unroll
      for (int r = 0; r < 4; ++r){
        int col = c0 + r;
        float su = acc_u[fi][mi][r];
        float v = acc_c[fi][mi][r] * SCALE - su / (1.f + expf(-su));
        ((float*)&o)[r] = (col > row) ? -INFINITY : v;
      }
      *(float4*)(out + (size_t)row * 1024 + c0) = o;
    }
}

// ---------------- K4: fused softmax + PV ------------------------------------
// Block = (bh, 16-row tile). Phase 1: row softmax from fin (f32) into padded
// LDS probs (bf16, stride 1032 -> 2-way bank alias = free). Phase 2: 4-wave
// K-split PV MFMA, A-frags from LDS, B from vcT; f32 reduce overlays LDS.
__global__ __launch_bounds__(256) void k_pv_soft(
    const float* __restrict__ fin, const unsigned short* __restrict__ vcT,
    unsigned short* __restrict__ O){
  __shared__ __align__(16) unsigned char smem[16 * 1032 * 2];  // 33 KB
  unsigned short* lp = (unsigned short*)smem;                  // probs [16][1032]
  float* red = (float*)smem;                                   // overlay (PV reduce)
  int t = threadIdx.x;
  int bh = blockIdx.x & 15, mt = 63 - (blockIdx.x >> 4);       // heavy first
  int m0 = mt * 16;
  int kceil = ((m0 + 16 + 31) >> 5) << 5;                      // K extent (mult of 32)
  // ---- phase 1: softmax of rows m0..m0+15 ----
  {
    int rl = t >> 4, sub = t & 15;                             // 16 threads/row
    int rloc = m0 + rl;
    const float* p = fin + (size_t)bh * 1048576 + (size_t)rloc * 1024;
    float4 v[16];
    float m = -INFINITY;
#pragma unroll
    for (int i = 0; i < 16; ++i){
      int c4 = (sub + 16*i) * 4;
      if (c4 < kceil){
        float4 xv = *(const float4*)(p + c4);
        v[i].x = (c4 + 0 <= rloc) ? xv.x : -INFINITY;
        v[i].y = (c4 + 1 <= rloc) ? xv.y : -INFINITY;
        v[i].z = (c4 + 2 <= rloc) ? xv.z : -INFINITY;
        v[i].w = (c4 + 3 <= rloc) ? xv.w : -INFINITY;
        m = fmaxf(m, fmaxf(fmaxf(v[i].x, v[i].y), fmaxf(v[i].z, v[i].w)));
      }
    }
#pragma unroll
    for (int off = 1; off < 16; off <<= 1) m = fmaxf(m, __shfl_xor(m, off));
    float s = 0.f;
#pragma unroll
    for (int i = 0; i < 16; ++i){
      int c4 = (sub + 16*i) * 4;
      if (c4 < kceil){
        v[i].x = expf(v[i].x - m); v[i].y = expf(v[i].y - m);
        v[i].z = expf(v[i].z - m); v[i].w = expf(v[i].w - m);
        s += v[i].x + v[i].y + v[i].z + v[i].w;
      }
    }
#pragma unroll
    for (int off = 1; off < 16; off <<= 1) s += __shfl_xor(s, off);
    float inv = 1.f / s;
#pragma unroll
    for (int i = 0; i < 16; ++i){
      int c4 = (sub + 16*i) * 4;
      if (c4 < kceil){
        ushort4 o;
        o.x = f2bf(v[i].x * inv); o.y = f2bf(v[i].y * inv);
        o.z = f2bf(v[i].z * inv); o.w = f2bf(v[i].w * inv);
        *(ushort4*)(lp + rl * 1032 + c4) = o;
      }
    }
  }
  __syncthreads();
  // ---- phase 2: O[16x64] = probs @ v_c, 4-way K-split ----
  int lane = t & 63, l16 = lane & 15, quad = lane >> 4, w = t >> 6;
  const unsigned short* Bt = vcT + (size_t)bh * 65536;
  int ktot = kceil >> 5;
  int per = (ktot + 3) >> 2;
  int s0 = w * per, s1 = min(s0 + per, ktot);
  f32x4 acc[4] = {};
  for (int s = s0; s < s1; ++s){
    int k0 = s * 32;
    bf16x8 a = *(const bf16x8*)(lp + l16 * 1032 + k0 + quad * 8);
#pragma unroll
    for (int fi = 0; fi < 4; ++fi){
      bf16x8 b = ld8(Bt + (size_t)(fi*16 + l16) * 1024 + k0 + quad * 8);
      acc[fi] = mfma16(a, b, acc[fi]);
    }
  }
  __syncthreads();                          // probs LDS dead; overlay reduce
#pragma unroll
  for (int fi = 0; fi < 4; ++fi)
#pragma unroll
    for (int r = 0; r < 4; ++r)
      red[w * 1024 + (quad*4 + r) * 64 + fi*16 + l16] = acc[fi][r];
  __syncthreads();
  float4 a0 = ((const float4*)(red + 0*1024))[t];
  float4 a1 = ((const float4*)(red + 1*1024))[t];
  float4 a2 = ((const float4*)(red + 2*1024))[t];
  float4 a3 = ((const float4*)(red + 3*1024))[t];
  ushort4 o;
  o.x = f2bf(a0.x + a1.x + a2.x + a3.x);
  o.y = f2bf(a0.y + a1.y + a2.y + a3.y);
  o.z = f2bf(a0.z + a1.z + a2.z + a3.z);
  o.w = f2bf(a0.w + a1.w + a2.w + a3.w);
  int e = t * 4, row = e >> 6, col = e & 63;
  *(ushort4*)(O + (size_t)bh * 65536 + (size_t)(m0 + row) * 64 + col) = o;
}

// ---------------- K5: out(f32) = O_cat @ w_out, 4-way K-split ---------------
__global__ __launch_bounds__(256) void k_out(
    const unsigned short* __restrict__ O, const unsigned short* __restrict__ woT,
    float* __restrict__ out){
  __shared__ float red[4][1024];
  int t = threadIdx.x, lane = t & 63, l16 = lane & 15, quad = lane >> 4, w = t >> 6;
  int mt = blockIdx.x >> 3, nt = blockIdx.x & 7;
  int m0 = mt * 16, n0 = nt * 64;
  int r_ = m0 + l16, b_ = r_ >> 10, n_ = r_ & 1023;
  f32x4 acc[4] = {};
#pragma unroll
  for (int s = 0; s < 4; ++s){
    int kk = w * 128 + s * 32 + quad * 8;
    int h = kk >> 6, dd = kk & 63;
    bf16x8 a = ld8(O + (size_t)(b_*8 + h) * 65536 + (size_t)n_ * 64 + dd);
#pragma unroll
    for (int fi = 0; fi < 4; ++fi){
      bf16x8 b = ld8(woT + (size_t)(n0 + fi*16 + l16) * 512 + kk);
      acc[fi] = mfma16(a, b, acc[fi]);
    }
  }
#pragma unroll
  for (int fi = 0; fi < 4; ++fi)
#pragma unroll
    for (int r = 0; r < 4; ++r)
      red[w][(quad*4 + r) * 64 + fi*16 + l16] = acc[fi][r];
  __syncthreads();
  float4 a0 = ((const float4*)red[0])[t];
  float4 a1 = ((const float4*)red[1])[t];
  float4 a2 = ((const float4*)red[2])[t];
  float4 a3 = ((const float4*)red[3])[t];
  float4 o;
  o.x = a0.x + a1.x + a2.x + a3.x;
  o.y = a0.y + a1.y + a2.y + a3.y;
  o.z = a0.z + a1.z + a2.z + a3.z;
  o.w = a0.w + a1.w + a2.w + a3.w;
  int e = t * 4, row = e >> 6, col = e & 63;
  *(float4*)(out + (size_t)(m0 + row) * 512 + n0 + col) = o;
}

extern "C" void kernel_launch(void* const* d_in, const int* in_sizes, int n_in,
                              void* d_out, int out_size, void* d_ws, size_t ws_size,
                              hipStream_t stream){
  const float* x = (const float*)d_in[0];
  float* out = (float*)d_out;
  unsigned short* ws = (unsigned short*)d_ws;

  unsigned short* wT    = ws;                                   // 7*262144
  unsigned short* xb    = wT    + (size_t)7  * 262144;          // 1048576
  unsigned short* P     = xb    + (size_t)1048576;              // 96*65536
  unsigned short* vcT   = P     + (size_t)96 * 65536;           // 16*65536
  unsigned short* term1 = vcT   + (size_t)16 * 65536;           // 16*1048576
  unsigned short* sig   = term1 + (size_t)16 * 1048576;         // 16*1048576
  unsigned short* O     = sig   + (size_t)16 * 1048576;         // 16*65536
  float*          fin   = (float*)(O + (size_t)16 * 65536);     // 16*1048576 f32

  k_prep<<<1472, 256, 0, stream>>>(
      x,
      (const float*)d_in[1], (const float*)d_in[2], (const float*)d_in[3],
      (const float*)d_in[4], (const float*)d_in[5], (const float*)d_in[6],
      (const float*)d_in[7], xb, wT);
  k_proj<<<384, 256, 0, stream>>>(xb, wT, P);
  k_vct<<<256, 256, 0, stream>>>(P + (size_t)5*16*65536, vcT);
  k_qk<<<4608, 256, 0, stream>>>(P, term1, sig);
  k_scores<<<576, 256, 0, stream>>>(P, term1, sig, fin);
  k_pv_soft<<<1024, 256, 0, stream>>>(fin, vcT, O);
  k_out<<<1024, 256, 0, stream>>>(O, wT + (size_t)6 * 262144, out);
}

// Round 7
// 176.690 us; speedup vs baseline: 1.9182x; 1.0221x over previous
//
#include <hip/hip_runtime.h>
#include <math.h>

// Problem: b=2, h=8, n=1024, d=64, DIM=512. Inputs/outputs FLOAT32.
// Internal pipeline bf16 MFMA (f32 accumulate). SCALE = 1/8.

typedef __bf16 bf16x8 __attribute__((ext_vector_type(8)));
typedef float f32x4 __attribute__((ext_vector_type(4)));

#define SCALE 0.125f

// async global->LDS: lane deposits 16B at (wave-uniform base + lane*16)
#define GLL(g, l) __builtin_amdgcn_global_load_lds(                         \
    (const __attribute__((address_space(1))) void*)(g),                     \
    (__attribute__((address_space(3))) void*)(l), 16, 0, 0)

__device__ __forceinline__ unsigned short f2bf(float f){
  unsigned int x = __builtin_bit_cast(unsigned int, f);
  unsigned int r = (x + 0x7fffu + ((x >> 16) & 1u)) >> 16;  // RNE
  return (unsigned short)r;
}
__device__ __forceinline__ float bf2f(unsigned short u){
  unsigned int x = ((unsigned int)u) << 16;
  return __builtin_bit_cast(float, x);
}
__device__ __forceinline__ f32x4 mfma16(bf16x8 a, bf16x8 b, f32x4 c){
  return __builtin_amdgcn_mfma_f32_16x16x32_bf16(a, b, c, 0, 0, 0);
}
__device__ __forceinline__ bf16x8 ld8(const unsigned short* p){
  return *(const bf16x8*)p;
}

// ---------------- K0: x f32->bf16 (blocks 0..1023) + weight transpose -------
__global__ __launch_bounds__(256) void k_prep(
    const float* __restrict__ x,
    const float* __restrict__ w0, const float* __restrict__ w1,
    const float* __restrict__ w2, const float* __restrict__ w3,
    const float* __restrict__ w4, const float* __restrict__ w5,
    const float* __restrict__ w6,
    unsigned short* __restrict__ xb, unsigned short* __restrict__ wT){
  int t = threadIdx.x;
  if (blockIdx.x < 1024){
    int i = blockIdx.x * 256 + t;
    float4 v = ((const float4*)x)[i];
    ushort4 o; o.x = f2bf(v.x); o.y = f2bf(v.y); o.z = f2bf(v.z); o.w = f2bf(v.w);
    ((ushort4*)xb)[i] = o;
    return;
  }
  __shared__ float lds[64 * 65];
  int bx = blockIdx.x - 1024;                   // 448 = 7 mats * 64 tiles
  int mat = bx >> 6, tile = bx & 63, tr = tile >> 3, tc = tile & 7;
  int k0 = tr * 64, c0 = tc * 64;
  const float* src;
  switch (mat){
    case 0: src = w0; break; case 1: src = w1; break; case 2: src = w2; break;
    case 3: src = w3; break; case 4: src = w4; break; case 5: src = w5; break;
    default: src = w6; break;
  }
#pragma unroll
  for (int i = 0; i < 4; ++i){
    int r = (t >> 4) + i * 16, c4 = (t & 15) * 4;
    float4 v = *(const float4*)(src + (size_t)(k0 + r) * 512 + c0 + c4);
    lds[r * 65 + c4 + 0] = v.x; lds[r * 65 + c4 + 1] = v.y;
    lds[r * 65 + c4 + 2] = v.z; lds[r * 65 + c4 + 3] = v.w;
  }
  __syncthreads();
  unsigned short* dst = wT + (size_t)mat * 262144;
#pragma unroll
  for (int i = 0; i < 4; ++i){
    int oc = (t >> 4) + i * 16;
    int kq = (t & 15) * 4;
    ushort4 o;
    o.x = f2bf(lds[(kq + 0) * 65 + oc]);
    o.y = f2bf(lds[(kq + 1) * 65 + oc]);
    o.z = f2bf(lds[(kq + 2) * 65 + oc]);
    o.w = f2bf(lds[(kq + 3) * 65 + oc]);
    *(ushort4*)(dst + (size_t)(c0 + oc) * 512 + k0 + kq) = o;
  }
}

// ---------------- K1: fused projections: [2048,512] @ [512,3072] ------------
__global__ __launch_bounds__(256) void k_proj(
    const unsigned short* __restrict__ xb, const unsigned short* __restrict__ wT,
    unsigned short* __restrict__ P){
  __shared__ unsigned short sA[128 * 32], sB[128 * 32];
  int t = threadIdx.x, lane = t & 63, l16 = lane & 15, quad = lane >> 4;
  int w = t >> 6, wm = w >> 1, wn = w & 1;
  int bx = blockIdx.x;                       // 384 = 16 Mtiles * 24 Ntiles
  int mt = bx / 24, nt = bx - mt * 24;
  int M0 = mt * 128, N0 = nt * 128;
  int matb = N0 >> 9;
  int nin = N0 & 511;
  int srow = (lane >> 2), scol = (lane & 3) * 8;
  const unsigned short* gA = xb + (size_t)(M0 + w*32 + srow) * 512 + scol;
  const unsigned short* gB = wT + (size_t)matb * 262144
                               + (size_t)(nin + w*32 + srow) * 512 + scol;
  unsigned short* lA = sA + (w*32) * 32;
  unsigned short* lB = sB + (w*32) * 32;
  f32x4 acc[4][4] = {};
  for (int k0 = 0; k0 < 512; k0 += 32){
    GLL(gA + k0,            lA);
    GLL(gA + k0 + 16*512,   lA + 16*32);
    GLL(gB + k0,            lB);
    GLL(gB + k0 + 16*512,   lB + 16*32);
    __syncthreads();
    bf16x8 aw[4], ax[4];
#pragma unroll
    for (int fi = 0; fi < 4; ++fi)
      aw[fi] = *(const bf16x8*)(sB + (wn*64 + fi*16 + l16) * 32 + quad * 8);
#pragma unroll
    for (int mi = 0; mi < 4; ++mi)
      ax[mi] = *(const bf16x8*)(sA + (wm*64 + mi*16 + l16) * 32 + quad * 8);
#pragma unroll
    for (int fi = 0; fi < 4; ++fi)
#pragma unroll
      for (int mi = 0; mi < 4; ++mi)
        acc[fi][mi] = mfma16(aw[fi], ax[mi], acc[fi][mi]);
    __syncthreads();
  }
#pragma unroll
  for (int fi = 0; fi < 4; ++fi)
#pragma unroll
    for (int mi = 0; mi < 4; ++mi){
      int row = M0 + wm*64 + mi*16 + l16;
      int b_ = row >> 10, n_ = row & 1023;
      int c0 = N0 + wn*64 + fi*16 + quad*4;
      int h = (c0 & 511) >> 6, d = c0 & 63;
      int bh = b_*8 + h;
      ushort4 o;
      o.x = f2bf(acc[fi][mi][0]); o.y = f2bf(acc[fi][mi][1]);
      o.z = f2bf(acc[fi][mi][2]); o.w = f2bf(acc[fi][mi][3]);
      *(ushort4*)(P + (size_t)(matb*16 + bh) * 65536 + (size_t)n_ * 64 + d) = o;
    }
}

// ---------------- K2: merged  vcT transpose (blocks 0..255)  +  qk ----------
__global__ __launch_bounds__(256) void k_qk_vct(
    const unsigned short* __restrict__ P,
    unsigned short* __restrict__ term1, unsigned short* __restrict__ sig,
    unsigned short* __restrict__ vcT){
  __shared__ unsigned short lds[64 * 72];
  int t = threadIdx.x;
  if (blockIdx.x < 256){
    // ---- vcT[bh][d][n] = P5[bh][n][d] ----
    int bh = blockIdx.x >> 4, nt = blockIdx.x & 15;
    int N0 = nt * 64;
    const unsigned short* src = P + (size_t)(5*16 + bh) * 65536 + (size_t)N0 * 64;
#pragma unroll
    for (int it = 0; it < 2; ++it){
      int id = it * 256 + t;
      int r = id >> 3, c8 = (id & 7) * 8;
      ushort4 v0 = *(const ushort4*)(src + r * 64 + c8);
      ushort4 v1 = *(const ushort4*)(src + r * 64 + c8 + 4);
      *(ushort4*)(lds + r * 72 + c8) = v0;
      *(ushort4*)(lds + r * 72 + c8 + 4) = v1;
    }
    __syncthreads();
    unsigned short* dst = vcT + (size_t)bh * 65536;
#pragma unroll
    for (int it = 0; it < 2; ++it){
      int id = it * 256 + t;
      int dd = id >> 3, n8 = (id & 7) * 8;
      ushort4 a, b;
      a.x = lds[(n8+0)*72 + dd]; a.y = lds[(n8+1)*72 + dd];
      a.z = lds[(n8+2)*72 + dd]; a.w = lds[(n8+3)*72 + dd];
      b.x = lds[(n8+4)*72 + dd]; b.y = lds[(n8+5)*72 + dd];
      b.z = lds[(n8+6)*72 + dd]; b.w = lds[(n8+7)*72 + dd];
      *(ushort4*)(dst + (size_t)dd * 1024 + N0 + n8) = a;
      *(ushort4*)(dst + (size_t)dd * 1024 + N0 + n8 + 4) = b;
    }
    return;
  }
  // ---- qk: term1 (lower band) and sig (upper band) ----
  int gw = ((blockIdx.x - 256) * 256 + t) >> 6;       // 0..18431
  int lane = t & 63, l16 = lane & 15, quad = lane >> 4;
  int bhm = gw / 576;
  int idx = gw - bhm * 576;
  int bh = bhm >> 1, mat = bhm & 1;
  int B = 0;
  while (idx >= 8 * (B + 1) * (B + 2)) ++B;
  int r2 = idx - 8 * B * (B + 1);
  int per = 2 * (B + 1);
  int mt_in = r2 / per, sub = r2 - mt_in * per;
  int m0 = (B * 8 + mt_in) * 16, n0 = sub * 64;
  if (mat){ m0 = 1008 - m0; n0 = 960 - n0; }
  unsigned short* out = (mat ? sig : term1) + (size_t)bh * 1048576;
  int row = m0 + l16;
  bool zero_tile = mat ? (n0 + 63 <= m0) : (n0 > m0 + 15);
  if (zero_tile){
    ushort4 z = {0, 0, 0, 0};
#pragma unroll
    for (int f = 0; f < 4; ++f)
      *(ushort4*)(out + (size_t)row * 1024 + n0 + f*16 + quad*4) = z;
    return;
  }
  const unsigned short* A  = P + (size_t)((mat ? 0 : 3)*16 + bh) * 65536;
  const unsigned short* Bt = P + (size_t)((mat ? 1 : 2)*16 + bh) * 65536;
  f32x4 acc[4] = {};
  for (int k0 = 0; k0 < 64; k0 += 32){
    bf16x8 bi = ld8(A + (size_t)(m0 + l16) * 64 + k0 + quad * 8);
#pragma unroll
    for (int f = 0; f < 4; ++f){
      bf16x8 aj = ld8(Bt + (size_t)(n0 + f*16 + l16) * 64 + k0 + quad * 8);
      acc[f] = mfma16(aj, bi, acc[f]);
    }
  }
#pragma unroll
  for (int f = 0; f < 4; ++f){
    int c0 = n0 + f*16 + quad*4;
    ushort4 o;
#pragma unroll
    for (int r = 0; r < 4; ++r){
      int col = c0 + r;
      float v = acc[f][r] * SCALE;
      unsigned short res;
      if (mat == 0) res = (col <= row) ? f2bf(v) : (unsigned short)0;
      else          res = (col >  row) ? f2bf(1.f / (1.f + expf(-v))) : (unsigned short)0;
      ((unsigned short*)&o)[r] = res;
    }
    *(ushort4*)(out + (size_t)row * 1024 + c0) = o;
  }
}

// ---------------- K3: finb(bf16) = S_c - silu(S_u), lower tiles only --------
// Phase 1 (S_u): GLL-staged m97-style; phase 2 (S_c, K=64): barrier-free
// direct L3-hit fragment loads. Upper-triangle lanes store unmasked finite
// values; the consumer masks col>row.
__global__ __launch_bounds__(256) void k_scores(
    const unsigned short* __restrict__ P, const unsigned short* __restrict__ term1,
    const unsigned short* __restrict__ sig, unsigned short* __restrict__ finb){
  __shared__ unsigned short sA[128 * 32], sB[128 * 32];
  int t = threadIdx.x;
  int bh = blockIdx.x & 15, tt = blockIdx.x >> 4;
  int k = 1, T = 0;
  while (tt >= T + k){ T += k; ++k; }
  int delta = 8 - k;
  int tj = tt - T, ti = tj + delta;
  int M0 = ti * 128, N0 = tj * 128;
  size_t sbase = (size_t)bh * 1048576;
  int lane = t & 63, l16 = lane & 15, quad = lane >> 4;
  int w = t >> 6, wm = w >> 1, wn = w & 1;
  int srow = (lane >> 2), scol = (lane & 3) * 8;
  unsigned short* lA = sA + (w*32) * 32;
  unsigned short* lB = sB + (w*32) * 32;
  f32x4 acc_u[4][4] = {};
  f32x4 acc_c[4][4] = {};
  {
    const unsigned short* gA = term1 + sbase + (size_t)(M0 + w*32 + srow) * 1024 + scol;
    const unsigned short* gB = sig   + sbase + (size_t)(N0 + w*32 + srow) * 1024 + scol;
    int steps = (delta + 1) * 4;
    for (int s = 0; s < steps; ++s){
      int j0 = N0 + s * 32;
      GLL(gA + j0,             lA);
      GLL(gA + j0 + 16*1024,   lA + 16*32);
      GLL(gB + j0,             lB);
      GLL(gB + j0 + 16*1024,   lB + 16*32);
      __syncthreads();
      bf16x8 af[4], bfr[4];
#pragma unroll
      for (int mi = 0; mi < 4; ++mi)
        af[mi] = *(const bf16x8*)(sA + (wm*64 + mi*16 + l16) * 32 + quad * 8);
#pragma unroll
      for (int fi = 0; fi < 4; ++fi)
        bfr[fi] = *(const bf16x8*)(sB + (wn*64 + fi*16 + l16) * 32 + quad * 8);
#pragma unroll
      for (int fi = 0; fi < 4; ++fi)
#pragma unroll
        for (int mi = 0; mi < 4; ++mi)
          acc_u[fi][mi] = mfma16(bfr[fi], af[mi], acc_u[fi][mi]);
      __syncthreads();
    }
  }
  {
    const unsigned short* Qc = P + (size_t)(3*16 + bh) * 65536;
    const unsigned short* Kc = P + (size_t)(4*16 + bh) * 65536;
#pragma unroll
    for (int k0 = 0; k0 < 64; k0 += 32){
      bf16x8 af[4], bfr[4];
#pragma unroll
      for (int mi = 0; mi < 4; ++mi)
        af[mi] = ld8(Qc + (size_t)(M0 + wm*64 + mi*16 + l16) * 64 + k0 + quad * 8);
#pragma unroll
      for (int fi = 0; fi < 4; ++fi)
        bfr[fi] = ld8(Kc + (size_t)(N0 + wn*64 + fi*16 + l16) * 64 + k0 + quad * 8);
#pragma unroll
      for (int fi = 0; fi < 4; ++fi)
#pragma unroll
        for (int mi = 0; mi < 4; ++mi)
          acc_c[fi][mi] = mfma16(bfr[fi], af[mi], acc_c[fi][mi]);
    }
  }
  unsigned short* out = finb + sbase;
#pragma unroll
  for (int fi = 0; fi < 4; ++fi)
#pragma unroll
    for (int mi = 0; mi < 4; ++mi){
      int row = M0 + wm*64 + mi*16 + l16;
      int c0 = N0 + wn*64 + fi*16 + quad*4;
      ushort4 o;
#pragma unroll
      for (int r = 0; r < 4; ++r){
        float su = acc_u[fi][mi][r];
        float v = acc_c[fi][mi][r] * SCALE - su / (1.f + expf(-su));
        ((unsigned short*)&o)[r] = f2bf(v);   // col>row masked downstream
      }
      *(ushort4*)(out + (size_t)row * 1024 + c0) = o;
    }
}

// ---------------- K4: fused softmax + PV (finb is bf16 now) -----------------
__global__ __launch_bounds__(256) void k_pv_soft(
    const unsigned short* __restrict__ finb, const unsigned short* __restrict__ vcT,
    unsigned short* __restrict__ O){
  __shared__ __align__(16) unsigned char smem[16 * 1032 * 2];  // 33 KB
  unsigned short* lp = (unsigned short*)smem;                  // probs [16][1032]
  float* red = (float*)smem;                                   // overlay (PV reduce)
  int t = threadIdx.x;
  int bh = blockIdx.x & 15, mt = 63 - (blockIdx.x >> 4);       // heavy first
  int m0 = mt * 16;
  int kceil = ((m0 + 16 + 31) >> 5) << 5;                      // mult of 32
  // ---- phase 1: softmax of rows m0..m0+15 (16 threads/row, 8 bf16/ld) ----
  {
    int rl = t >> 4, sub = t & 15;
    int rloc = m0 + rl;
    const unsigned short* p = finb + (size_t)bh * 1048576 + (size_t)rloc * 1024;
    float v[8][8];
    float m = -INFINITY;
#pragma unroll
    for (int i = 0; i < 8; ++i){
      int c8 = (sub + 16*i) * 8;
      if (c8 < kceil){
        ushort4 u0 = *(const ushort4*)(p + c8);
        ushort4 u1 = *(const ushort4*)(p + c8 + 4);
        float vv[8] = {bf2f(u0.x), bf2f(u0.y), bf2f(u0.z), bf2f(u0.w),
                       bf2f(u1.x), bf2f(u1.y), bf2f(u1.z), bf2f(u1.w)};
#pragma unroll
        for (int e = 0; e < 8; ++e){
          v[i][e] = (c8 + e <= rloc) ? vv[e] : -INFINITY;
          m = fmaxf(m, v[i][e]);
        }
      }
    }
#pragma unroll
    for (int off = 1; off < 16; off <<= 1) m = fmaxf(m, __shfl_xor(m, off));
    float s = 0.f;
#pragma unroll
    for (int i = 0; i < 8; ++i){
      int c8 = (sub + 16*i) * 8;
      if (c8 < kceil){
#pragma unroll
        for (int e = 0; e < 8; ++e){
          v[i][e] = expf(v[i][e] - m);
          s += v[i][e];
        }
      }
    }
#pragma unroll
    for (int off = 1; off < 16; off <<= 1) s += __shfl_xor(s, off);
    float inv = 1.f / s;
#pragma unroll
    for (int i = 0; i < 8; ++i){
      int c8 = (sub + 16*i) * 8;
      if (c8 < kceil){
        ushort4 o0, o1;
        o0.x = f2bf(v[i][0] * inv); o0.y = f2bf(v[i][1] * inv);
        o0.z = f2bf(v[i][2] * inv); o0.w = f2bf(v[i][3] * inv);
        o1.x = f2bf(v[i][4] * inv); o1.y = f2bf(v[i][5] * inv);
        o1.z = f2bf(v[i][6] * inv); o1.w = f2bf(v[i][7] * inv);
        *(ushort4*)(lp + rl * 1032 + c8) = o0;
        *(ushort4*)(lp + rl * 1032 + c8 + 4) = o1;
      }
    }
  }
  __syncthreads();
  // ---- phase 2: O[16x64] = probs @ v_c, 4-way K-split ----
  int lane = t & 63, l16 = lane & 15, quad = lane >> 4, w = t >> 6;
  const unsigned short* Bt = vcT + (size_t)bh * 65536;
  int ktot = kceil >> 5;
  int per = (ktot + 3) >> 2;
  int s0 = w * per, s1 = min(s0 + per, ktot);
  f32x4 acc[4] = {};
  for (int s = s0; s < s1; ++s){
    int k0 = s * 32;
    bf16x8 a = *(const bf16x8*)(lp + l16 * 1032 + k0 + quad * 8);
#pragma unroll
    for (int fi = 0; fi < 4; ++fi){
      bf16x8 b = ld8(Bt + (size_t)(fi*16 + l16) * 1024 + k0 + quad * 8);
      acc[fi] = mfma16(a, b, acc[fi]);
    }
  }
  __syncthreads();                          // probs LDS dead; overlay reduce
#pragma unroll
  for (int fi = 0; fi < 4; ++fi)
#pragma unroll
    for (int r = 0; r < 4; ++r)
      red[w * 1024 + (quad*4 + r) * 64 + fi*16 + l16] = acc[fi][r];
  __syncthreads();
  float4 a0 = ((const float4*)(red + 0*1024))[t];
  float4 a1 = ((const float4*)(red + 1*1024))[t];
  float4 a2 = ((const float4*)(red + 2*1024))[t];
  float4 a3 = ((const float4*)(red + 3*1024))[t];
  ushort4 o;
  o.x = f2bf(a0.x + a1.x + a2.x + a3.x);
  o.y = f2bf(a0.y + a1.y + a2.y + a3.y);
  o.z = f2bf(a0.z + a1.z + a2.z + a3.z);
  o.w = f2bf(a0.w + a1.w + a2.w + a3.w);
  int e = t * 4, row = e >> 6, col = e & 63;
  *(ushort4*)(O + (size_t)bh * 65536 + (size_t)(m0 + row) * 64 + col) = o;
}

// ---------------- K5: out(f32) = O_cat @ w_out, 4-way K-split ---------------
__global__ __launch_bounds__(256) void k_out(
    const unsigned short* __restrict__ O, const unsigned short* __restrict__ woT,
    float* __restrict__ out){
  __shared__ float red[4][1024];
  int t = threadIdx.x, lane = t & 63, l16 = lane & 15, quad = lane >> 4, w = t >> 6;
  int mt = blockIdx.x >> 3, nt = blockIdx.x & 7;
  int m0 = mt * 16, n0 = nt * 64;
  int r_ = m0 + l16, b_ = r_ >> 10, n_ = r_ & 1023;
  f32x4 acc[4] = {};
#pragma unroll
  for (int s = 0; s < 4; ++s){
    int kk = w * 128 + s * 32 + quad * 8;
    int h = kk >> 6, dd = kk & 63;
    bf16x8 a = ld8(O + (size_t)(b_*8 + h) * 65536 + (size_t)n_ * 64 + dd);
#pragma unroll
    for (int fi = 0; fi < 4; ++fi){
      bf16x8 b = ld8(woT + (size_t)(n0 + fi*16 + l16) * 512 + kk);
      acc[fi] = mfma16(a, b, acc[fi]);
    }
  }
#pragma unroll
  for (int fi = 0; fi < 4; ++fi)
#pragma unroll
    for (int r = 0; r < 4; ++r)
      red[w][(quad*4 + r) * 64 + fi*16 + l16] = acc[fi][r];
  __syncthreads();
  float4 a0 = ((const float4*)red[0])[t];
  float4 a1 = ((const float4*)red[1])[t];
  float4 a2 = ((const float4*)red[2])[t];
  float4 a3 = ((const float4*)red[3])[t];
  float4 o;
  o.x = a0.x + a1.x + a2.x + a3.x;
  o.y = a0.y + a1.y + a2.y + a3.y;
  o.z = a0.z + a1.z + a2.z + a3.z;
  o.w = a0.w + a1.w + a2.w + a3.w;
  int e = t * 4, row = e >> 6, col = e & 63;
  *(float4*)(out + (size_t)(m0 + row) * 512 + n0 + col) = o;
}

extern "C" void kernel_launch(void* const* d_in, const int* in_sizes, int n_in,
                              void* d_out, int out_size, void* d_ws, size_t ws_size,
                              hipStream_t stream){
  const float* x = (const float*)d_in[0];
  float* out = (float*)d_out;
  unsigned short* ws = (unsigned short*)d_ws;

  unsigned short* wT    = ws;                                   // 7*262144
  unsigned short* xb    = wT    + (size_t)7  * 262144;          // 1048576
  unsigned short* P     = xb    + (size_t)1048576;              // 96*65536
  unsigned short* vcT   = P     + (size_t)96 * 65536;           // 16*65536
  unsigned short* term1 = vcT   + (size_t)16 * 65536;           // 16*1048576
  unsigned short* sig   = term1 + (size_t)16 * 1048576;         // 16*1048576
  unsigned short* O     = sig   + (size_t)16 * 1048576;         // 16*65536
  unsigned short* finb  = O     + (size_t)16 * 65536;           // 16*1048576 bf16

  k_prep<<<1472, 256, 0, stream>>>(
      x,
      (const float*)d_in[1], (const float*)d_in[2], (const float*)d_in[3],
      (const float*)d_in[4], (const float*)d_in[5], (const float*)d_in[6],
      (const float*)d_in[7], xb, wT);
  k_proj<<<384, 256, 0, stream>>>(xb, wT, P);
  k_qk_vct<<<4864, 256, 0, stream>>>(P, term1, sig, vcT);
  k_scores<<<576, 256, 0, stream>>>(P, term1, sig, finb);
  k_pv_soft<<<1024, 256, 0, stream>>>(finb, vcT, O);
  k_out<<<1024, 256, 0, stream>>>(O, wT + (size_t)6 * 262144, out);
}

// Round 8
// 171.765 us; speedup vs baseline: 1.9732x; 1.0287x over previous
//
#include <hip/hip_runtime.h>
#include <math.h>

// Problem: b=2, h=8, n=1024, d=64, DIM=512. Inputs/outputs FLOAT32.
// Internal pipeline bf16 MFMA (f32 accumulate). SCALE = 1/8.

typedef __bf16 bf16x8 __attribute__((ext_vector_type(8)));
typedef float f32x4 __attribute__((ext_vector_type(4)));

#define SCALE 0.125f

// async global->LDS: lane deposits 16B at (wave-uniform base + lane*16)
#define GLL(g, l) __builtin_amdgcn_global_load_lds(                         \
    (const __attribute__((address_space(1))) void*)(g),                     \
    (__attribute__((address_space(3))) void*)(l), 16, 0, 0)

__device__ __forceinline__ unsigned short f2bf(float f){
  unsigned int x = __builtin_bit_cast(unsigned int, f);
  unsigned int r = (x + 0x7fffu + ((x >> 16) & 1u)) >> 16;  // RNE
  return (unsigned short)r;
}
__device__ __forceinline__ float bf2f(unsigned short u){
  unsigned int x = ((unsigned int)u) << 16;
  return __builtin_bit_cast(float, x);
}
__device__ __forceinline__ f32x4 mfma16(bf16x8 a, bf16x8 b, f32x4 c){
  return __builtin_amdgcn_mfma_f32_16x16x32_bf16(a, b, c, 0, 0, 0);
}
__device__ __forceinline__ bf16x8 ld8(const unsigned short* p){
  return *(const bf16x8*)p;
}

// ---------------- K0: x f32->bf16 (blocks 0..1023) + weight transpose -------
__global__ __launch_bounds__(256) void k_prep(
    const float* __restrict__ x,
    const float* __restrict__ w0, const float* __restrict__ w1,
    const float* __restrict__ w2, const float* __restrict__ w3,
    const float* __restrict__ w4, const float* __restrict__ w5,
    const float* __restrict__ w6,
    unsigned short* __restrict__ xb, unsigned short* __restrict__ wT){
  int t = threadIdx.x;
  if (blockIdx.x < 1024){
    int i = blockIdx.x * 256 + t;
    float4 v = ((const float4*)x)[i];
    ushort4 o; o.x = f2bf(v.x); o.y = f2bf(v.y); o.z = f2bf(v.z); o.w = f2bf(v.w);
    ((ushort4*)xb)[i] = o;
    return;
  }
  __shared__ float lds[64 * 65];
  int bx = blockIdx.x - 1024;                   // 448 = 7 mats * 64 tiles
  int mat = bx >> 6, tile = bx & 63, tr = tile >> 3, tc = tile & 7;
  int k0 = tr * 64, c0 = tc * 64;
  const float* src;
  switch (mat){
    case 0: src = w0; break; case 1: src = w1; break; case 2: src = w2; break;
    case 3: src = w3; break; case 4: src = w4; break; case 5: src = w5; break;
    default: src = w6; break;
  }
#pragma unroll
  for (int i = 0; i < 4; ++i){
    int r = (t >> 4) + i * 16, c4 = (t & 15) * 4;
    float4 v = *(const float4*)(src + (size_t)(k0 + r) * 512 + c0 + c4);
    lds[r * 65 + c4 + 0] = v.x; lds[r * 65 + c4 + 1] = v.y;
    lds[r * 65 + c4 + 2] = v.z; lds[r * 65 + c4 + 3] = v.w;
  }
  __syncthreads();
  unsigned short* dst = wT + (size_t)mat * 262144;
#pragma unroll
  for (int i = 0; i < 4; ++i){
    int oc = (t >> 4) + i * 16;
    int kq = (t & 15) * 4;
    ushort4 o;
    o.x = f2bf(lds[(kq + 0) * 65 + oc]);
    o.y = f2bf(lds[(kq + 1) * 65 + oc]);
    o.z = f2bf(lds[(kq + 2) * 65 + oc]);
    o.w = f2bf(lds[(kq + 3) * 65 + oc]);
    *(ushort4*)(dst + (size_t)(c0 + oc) * 512 + k0 + kq) = o;
  }
}

// ---------------- K1: fused projections: [2048,512] @ [512,3072] ------------
__global__ __launch_bounds__(256) void k_proj(
    const unsigned short* __restrict__ xb, const unsigned short* __restrict__ wT,
    unsigned short* __restrict__ P){
  __shared__ unsigned short sA[128 * 32], sB[128 * 32];
  int t = threadIdx.x, lane = t & 63, l16 = lane & 15, quad = lane >> 4;
  int w = t >> 6, wm = w >> 1, wn = w & 1;
  int bx = blockIdx.x;                       // 384 = 16 Mtiles * 24 Ntiles
  int mt = bx / 24, nt = bx - mt * 24;
  int M0 = mt * 128, N0 = nt * 128;
  int matb = N0 >> 9;
  int nin = N0 & 511;
  int srow = (lane >> 2), scol = (lane & 3) * 8;
  const unsigned short* gA = xb + (size_t)(M0 + w*32 + srow) * 512 + scol;
  const unsigned short* gB = wT + (size_t)matb * 262144
                               + (size_t)(nin + w*32 + srow) * 512 + scol;
  unsigned short* lA = sA + (w*32) * 32;
  unsigned short* lB = sB + (w*32) * 32;
  f32x4 acc[4][4] = {};
  for (int k0 = 0; k0 < 512; k0 += 32){
    GLL(gA + k0,            lA);
    GLL(gA + k0 + 16*512,   lA + 16*32);
    GLL(gB + k0,            lB);
    GLL(gB + k0 + 16*512,   lB + 16*32);
    __syncthreads();
    bf16x8 aw[4], ax[4];
#pragma unroll
    for (int fi = 0; fi < 4; ++fi)
      aw[fi] = *(const bf16x8*)(sB + (wn*64 + fi*16 + l16) * 32 + quad * 8);
#pragma unroll
    for (int mi = 0; mi < 4; ++mi)
      ax[mi] = *(const bf16x8*)(sA + (wm*64 + mi*16 + l16) * 32 + quad * 8);
#pragma unroll
    for (int fi = 0; fi < 4; ++fi)
#pragma unroll
      for (int mi = 0; mi < 4; ++mi)
        acc[fi][mi] = mfma16(aw[fi], ax[mi], acc[fi][mi]);
    __syncthreads();
  }
#pragma unroll
  for (int fi = 0; fi < 4; ++fi)
#pragma unroll
    for (int mi = 0; mi < 4; ++mi){
      int row = M0 + wm*64 + mi*16 + l16;
      int b_ = row >> 10, n_ = row & 1023;
      int c0 = N0 + wn*64 + fi*16 + quad*4;
      int h = (c0 & 511) >> 6, d = c0 & 63;
      int bh = b_*8 + h;
      ushort4 o;
      o.x = f2bf(acc[fi][mi][0]); o.y = f2bf(acc[fi][mi][1]);
      o.z = f2bf(acc[fi][mi][2]); o.w = f2bf(acc[fi][mi][3]);
      *(ushort4*)(P + (size_t)(matb*16 + bh) * 65536 + (size_t)n_ * 64 + d) = o;
    }
}

// ---------------- K2: vct (blocks 0..255) + qk as 128x128 GLL-staged tiles --
// term1: 36 lower tiles/bh; sig: 36 upper tiles/bh. 16bh*72 + 256 = 1408 blks.
__global__ __launch_bounds__(256) void k_qk_vct(
    const unsigned short* __restrict__ P,
    unsigned short* __restrict__ term1, unsigned short* __restrict__ sig,
    unsigned short* __restrict__ vcT){
  int t = threadIdx.x;
  if (blockIdx.x < 256){
    __shared__ unsigned short lds[64 * 72];
    int bh = blockIdx.x >> 4, nt = blockIdx.x & 15;
    int N0 = nt * 64;
    const unsigned short* src = P + (size_t)(5*16 + bh) * 65536 + (size_t)N0 * 64;
#pragma unroll
    for (int it = 0; it < 2; ++it){
      int id = it * 256 + t;
      int r = id >> 3, c8 = (id & 7) * 8;
      ushort4 v0 = *(const ushort4*)(src + r * 64 + c8);
      ushort4 v1 = *(const ushort4*)(src + r * 64 + c8 + 4);
      *(ushort4*)(lds + r * 72 + c8) = v0;
      *(ushort4*)(lds + r * 72 + c8 + 4) = v1;
    }
    __syncthreads();
    unsigned short* dst = vcT + (size_t)bh * 65536;
#pragma unroll
    for (int it = 0; it < 2; ++it){
      int id = it * 256 + t;
      int dd = id >> 3, n8 = (id & 7) * 8;
      ushort4 a, b;
      a.x = lds[(n8+0)*72 + dd]; a.y = lds[(n8+1)*72 + dd];
      a.z = lds[(n8+2)*72 + dd]; a.w = lds[(n8+3)*72 + dd];
      b.x = lds[(n8+4)*72 + dd]; b.y = lds[(n8+5)*72 + dd];
      b.z = lds[(n8+6)*72 + dd]; b.w = lds[(n8+7)*72 + dd];
      *(ushort4*)(dst + (size_t)dd * 1024 + N0 + n8) = a;
      *(ushort4*)(dst + (size_t)dd * 1024 + N0 + n8 + 4) = b;
    }
    return;
  }
  __shared__ unsigned short sA[128 * 32], sB[128 * 32];
  int id = blockIdx.x - 256;
  int bh = id & 15, tt = id >> 4;              // tt in [0,72)
  int mat = (tt >= 36);                        // 0=term1, 1=sig
  int tl = mat ? tt - 36 : tt;
  // decode tl -> lower-tri (ti,tj), ti>=tj
  int ti = 0;
  while (tl >= ti + 1){ tl -= ti + 1; ++ti; }
  int tj = tl;
  int R0, C0;
  const unsigned short *Asrc, *Bsrc;
  if (!mat){ R0 = ti * 128; C0 = tj * 128;     // term1 rows=i(ti), cols=j(tj)
             Asrc = P + (size_t)(3*16 + bh) * 65536;      // q_c
             Bsrc = P + (size_t)(2*16 + bh) * 65536; }    // v_u
  else     { R0 = tj * 128; C0 = ti * 128;     // sig rows=k(tj), cols=j(ti)
             Asrc = P + (size_t)(0*16 + bh) * 65536;      // q_u
             Bsrc = P + (size_t)(1*16 + bh) * 65536; }    // k_u
  int lane = t & 63, l16 = lane & 15, quad = lane >> 4;
  int w = t >> 6, wm = w >> 1, wn = w & 1;
  int srow = lane >> 2, scol = (lane & 3) * 8;
  const unsigned short* gA = Asrc + (size_t)(R0 + w*32 + srow) * 64 + scol;
  const unsigned short* gB = Bsrc + (size_t)(C0 + w*32 + srow) * 64 + scol;
  unsigned short* lA = sA + (w*32) * 32;
  unsigned short* lB = sB + (w*32) * 32;
  f32x4 acc[4][4] = {};                        // [fi=col grp][mi=row grp]
#pragma unroll
  for (int k0 = 0; k0 < 64; k0 += 32){
    GLL(gA + k0,           lA);
    GLL(gA + k0 + 16*64,   lA + 16*32);
    GLL(gB + k0,           lB);
    GLL(gB + k0 + 16*64,   lB + 16*32);
    __syncthreads();
    bf16x8 af[4], bfr[4];
#pragma unroll
    for (int mi = 0; mi < 4; ++mi)
      af[mi] = *(const bf16x8*)(sA + (wm*64 + mi*16 + l16) * 32 + quad * 8);
#pragma unroll
    for (int fi = 0; fi < 4; ++fi)
      bfr[fi] = *(const bf16x8*)(sB + (wn*64 + fi*16 + l16) * 32 + quad * 8);
#pragma unroll
    for (int fi = 0; fi < 4; ++fi)
#pragma unroll
      for (int mi = 0; mi < 4; ++mi)
        acc[fi][mi] = mfma16(bfr[fi], af[mi], acc[fi][mi]);
    __syncthreads();
  }
  unsigned short* out = (mat ? sig : term1) + (size_t)bh * 1048576;
#pragma unroll
  for (int fi = 0; fi < 4; ++fi)
#pragma unroll
    for (int mi = 0; mi < 4; ++mi){
      int row = R0 + wm*64 + mi*16 + l16;
      int c0 = C0 + wn*64 + fi*16 + quad*4;
      ushort4 o;
#pragma unroll
      for (int r = 0; r < 4; ++r){
        int col = c0 + r;
        float v = acc[fi][mi][r] * SCALE;
        unsigned short res;
        if (!mat) res = (col <= row) ? f2bf(v) : (unsigned short)0;
        else      res = (col >  row) ? f2bf(1.f / (1.f + expf(-v))) : (unsigned short)0;
        ((unsigned short*)&o)[r] = res;
      }
      *(ushort4*)(out + (size_t)row * 1024 + c0) = o;
    }
}

// ---------------- K3: finb(bf16) = S_c - silu(S_u), lower tiles only --------
__global__ __launch_bounds__(256) void k_scores(
    const unsigned short* __restrict__ P, const unsigned short* __restrict__ term1,
    const unsigned short* __restrict__ sig, unsigned short* __restrict__ finb){
  __shared__ unsigned short sA[128 * 32], sB[128 * 32];
  int t = threadIdx.x;
  int bh = blockIdx.x & 15, tt = blockIdx.x >> 4;
  int k = 1, T = 0;
  while (tt >= T + k){ T += k; ++k; }
  int delta = 8 - k;
  int tj = tt - T, ti = tj + delta;
  int M0 = ti * 128, N0 = tj * 128;
  size_t sbase = (size_t)bh * 1048576;
  int lane = t & 63, l16 = lane & 15, quad = lane >> 4;
  int w = t >> 6, wm = w >> 1, wn = w & 1;
  int srow = (lane >> 2), scol = (lane & 3) * 8;
  unsigned short* lA = sA + (w*32) * 32;
  unsigned short* lB = sB + (w*32) * 32;
  f32x4 acc_u[4][4] = {};
  f32x4 acc_c[4][4] = {};
  {
    const unsigned short* gA = term1 + sbase + (size_t)(M0 + w*32 + srow) * 1024 + scol;
    const unsigned short* gB = sig   + sbase + (size_t)(N0 + w*32 + srow) * 1024 + scol;
    int steps = (delta + 1) * 4;
    for (int s = 0; s < steps; ++s){
      int j0 = N0 + s * 32;
      GLL(gA + j0,             lA);
      GLL(gA + j0 + 16*1024,   lA + 16*32);
      GLL(gB + j0,             lB);
      GLL(gB + j0 + 16*1024,   lB + 16*32);
      __syncthreads();
      bf16x8 af[4], bfr[4];
#pragma unroll
      for (int mi = 0; mi < 4; ++mi)
        af[mi] = *(const bf16x8*)(sA + (wm*64 + mi*16 + l16) * 32 + quad * 8);
#pragma unroll
      for (int fi = 0; fi < 4; ++fi)
        bfr[fi] = *(const bf16x8*)(sB + (wn*64 + fi*16 + l16) * 32 + quad * 8);
#pragma unroll
      for (int fi = 0; fi < 4; ++fi)
#pragma unroll
        for (int mi = 0; mi < 4; ++mi)
          acc_u[fi][mi] = mfma16(bfr[fi], af[mi], acc_u[fi][mi]);
      __syncthreads();
    }
  }
  {
    const unsigned short* Qc = P + (size_t)(3*16 + bh) * 65536;
    const unsigned short* Kc = P + (size_t)(4*16 + bh) * 65536;
#pragma unroll
    for (int k0 = 0; k0 < 64; k0 += 32){
      bf16x8 af[4], bfr[4];
#pragma unroll
      for (int mi = 0; mi < 4; ++mi)
        af[mi] = ld8(Qc + (size_t)(M0 + wm*64 + mi*16 + l16) * 64 + k0 + quad * 8);
#pragma unroll
      for (int fi = 0; fi < 4; ++fi)
        bfr[fi] = ld8(Kc + (size_t)(N0 + wn*64 + fi*16 + l16) * 64 + k0 + quad * 8);
#pragma unroll
      for (int fi = 0; fi < 4; ++fi)
#pragma unroll
        for (int mi = 0; mi < 4; ++mi)
          acc_c[fi][mi] = mfma16(bfr[fi], af[mi], acc_c[fi][mi]);
    }
  }
  unsigned short* out = finb + sbase;
#pragma unroll
  for (int fi = 0; fi < 4; ++fi)
#pragma unroll
    for (int mi = 0; mi < 4; ++mi){
      int row = M0 + wm*64 + mi*16 + l16;
      int c0 = N0 + wn*64 + fi*16 + quad*4;
      ushort4 o;
#pragma unroll
      for (int r = 0; r < 4; ++r){
        float su = acc_u[fi][mi][r];
        float v = acc_c[fi][mi][r] * SCALE - su / (1.f + expf(-su));
        ((unsigned short*)&o)[r] = f2bf(v);   // col>row masked downstream
      }
      *(ushort4*)(out + (size_t)row * 1024 + c0) = o;
    }
}

// ---------------- K4: fused softmax + PV ------------------------------------
__global__ __launch_bounds__(256) void k_pv_soft(
    const unsigned short* __restrict__ finb, const unsigned short* __restrict__ vcT,
    unsigned short* __restrict__ O){
  __shared__ __align__(16) unsigned char smem[16 * 1032 * 2];  // 33 KB
  unsigned short* lp = (unsigned short*)smem;                  // probs [16][1032]
  float* red = (float*)smem;                                   // overlay (PV reduce)
  int t = threadIdx.x;
  int bh = blockIdx.x & 15, mt = 63 - (blockIdx.x >> 4);       // heavy first
  int m0 = mt * 16;
  int kceil = ((m0 + 16 + 31) >> 5) << 5;                      // mult of 32
  {
    int rl = t >> 4, sub = t & 15;
    int rloc = m0 + rl;
    const unsigned short* p = finb + (size_t)bh * 1048576 + (size_t)rloc * 1024;
    float v[8][8];
    float m = -INFINITY;
#pragma unroll
    for (int i = 0; i < 8; ++i){
      int c8 = (sub + 16*i) * 8;
      if (c8 < kceil){
        ushort4 u0 = *(const ushort4*)(p + c8);
        ushort4 u1 = *(const ushort4*)(p + c8 + 4);
        float vv[8] = {bf2f(u0.x), bf2f(u0.y), bf2f(u0.z), bf2f(u0.w),
                       bf2f(u1.x), bf2f(u1.y), bf2f(u1.z), bf2f(u1.w)};
#pragma unroll
        for (int e = 0; e < 8; ++e){
          v[i][e] = (c8 + e <= rloc) ? vv[e] : -INFINITY;
          m = fmaxf(m, v[i][e]);
        }
      }
    }
#pragma unroll
    for (int off = 1; off < 16; off <<= 1) m = fmaxf(m, __shfl_xor(m, off));
    float s = 0.f;
#pragma unroll
    for (int i = 0; i < 8; ++i){
      int c8 = (sub + 16*i) * 8;
      if (c8 < kceil){
#pragma unroll
        for (int e = 0; e < 8; ++e){
          v[i][e] = expf(v[i][e] - m);
          s += v[i][e];
        }
      }
    }
#pragma unroll
    for (int off = 1; off < 16; off <<= 1) s += __shfl_xor(s, off);
    float inv = 1.f / s;
#pragma unroll
    for (int i = 0; i < 8; ++i){
      int c8 = (sub + 16*i) * 8;
      if (c8 < kceil){
        ushort4 o0, o1;
        o0.x = f2bf(v[i][0] * inv); o0.y = f2bf(v[i][1] * inv);
        o0.z = f2bf(v[i][2] * inv); o0.w = f2bf(v[i][3] * inv);
        o1.x = f2bf(v[i][4] * inv); o1.y = f2bf(v[i][5] * inv);
        o1.z = f2bf(v[i][6] * inv); o1.w = f2bf(v[i][7] * inv);
        *(ushort4*)(lp + rl * 1032 + c8) = o0;
        *(ushort4*)(lp + rl * 1032 + c8 + 4) = o1;
      }
    }
  }
  __syncthreads();
  int lane = t & 63, l16 = lane & 15, quad = lane >> 4, w = t >> 6;
  const unsigned short* Bt = vcT + (size_t)bh * 65536;
  int ktot = kceil >> 5;
  int per = (ktot + 3) >> 2;
  int s0 = w * per, s1 = min(s0 + per, ktot);
  f32x4 acc[4] = {};
  for (int s = s0; s < s1; ++s){
    int k0 = s * 32;
    bf16x8 a = *(const bf16x8*)(lp + l16 * 1032 + k0 + quad * 8);
#pragma unroll
    for (int fi = 0; fi < 4; ++fi){
      bf16x8 b = ld8(Bt + (size_t)(fi*16 + l16) * 1024 + k0 + quad * 8);
      acc[fi] = mfma16(a, b, acc[fi]);
    }
  }
  __syncthreads();
#pragma unroll
  for (int fi = 0; fi < 4; ++fi)
#pragma unroll
    for (int r = 0; r < 4; ++r)
      red[w * 1024 + (quad*4 + r) * 64 + fi*16 + l16] = acc[fi][r];
  __syncthreads();
  float4 a0 = ((const float4*)(red + 0*1024))[t];
  float4 a1 = ((const float4*)(red + 1*1024))[t];
  float4 a2 = ((const float4*)(red + 2*1024))[t];
  float4 a3 = ((const float4*)(red + 3*1024))[t];
  ushort4 o;
  o.x = f2bf(a0.x + a1.x + a2.x + a3.x);
  o.y = f2bf(a0.y + a1.y + a2.y + a3.y);
  o.z = f2bf(a0.z + a1.z + a2.z + a3.z);
  o.w = f2bf(a0.w + a1.w + a2.w + a3.w);
  int e = t * 4, row = e >> 6, col = e & 63;
  *(ushort4*)(O + (size_t)bh * 65536 + (size_t)(m0 + row) * 64 + col) = o;
}

// ---------------- K5: out(f32) = O_cat @ w_out, 4-way K-split ---------------
__global__ __launch_bounds__(256) void k_out(
    const unsigned short* __restrict__ O, const unsigned short* __restrict__ woT,
    float* __restrict__ out){
  __shared__ float red[4][1024];
  int t = threadIdx.x, lane = t & 63, l16 = lane & 15, quad = lane >> 4, w = t >> 6;
  int mt = blockIdx.x >> 3, nt = blockIdx.x & 7;
  int m0 = mt * 16, n0 = nt * 64;
  int r_ = m0 + l16, b_ = r_ >> 10, n_ = r_ & 1023;
  f32x4 acc[4] = {};
#pragma unroll
  for (int s = 0; s < 4; ++s){
    int kk = w * 128 + s * 32 + quad * 8;
    int h = kk >> 6, dd = kk & 63;
    bf16x8 a = ld8(O + (size_t)(b_*8 + h) * 65536 + (size_t)n_ * 64 + dd);
#pragma unroll
    for (int fi = 0; fi < 4; ++fi){
      bf16x8 b = ld8(woT + (size_t)(n0 + fi*16 + l16) * 512 + kk);
      acc[fi] = mfma16(a, b, acc[fi]);
    }
  }
#pragma unroll
  for (int fi = 0; fi < 4; ++fi)
#pragma unroll
    for (int r = 0; r < 4; ++r)
      red[w][(quad*4 + r) * 64 + fi*16 + l16] = acc[fi][r];
  __syncthreads();
  float4 a0 = ((const float4*)red[0])[t];
  float4 a1 = ((const float4*)red[1])[t];
  float4 a2 = ((const float4*)red[2])[t];
  float4 a3 = ((const float4*)red[3])[t];
  float4 o;
  o.x = a0.x + a1.x + a2.x + a3.x;
  o.y = a0.y + a1.y + a2.y + a3.y;
  o.z = a0.z + a1.z + a2.z + a3.z;
  o.w = a0.w + a1.w + a2.w + a3.w;
  int e = t * 4, row = e >> 6, col = e & 63;
  *(float4*)(out + (size_t)(m0 + row) * 512 + n0 + col) = o;
}

extern "C" void kernel_launch(void* const* d_in, const int* in_sizes, int n_in,
                              void* d_out, int out_size, void* d_ws, size_t ws_size,
                              hipStream_t stream){
  const float* x = (const float*)d_in[0];
  float* out = (float*)d_out;
  unsigned short* ws = (unsigned short*)d_ws;

  unsigned short* wT    = ws;                                   // 7*262144
  unsigned short* xb    = wT    + (size_t)7  * 262144;          // 1048576
  unsigned short* P     = xb    + (size_t)1048576;              // 96*65536
  unsigned short* vcT   = P     + (size_t)96 * 65536;           // 16*65536
  unsigned short* term1 = vcT   + (size_t)16 * 65536;           // 16*1048576
  unsigned short* sig   = term1 + (size_t)16 * 1048576;         // 16*1048576
  unsigned short* O     = sig   + (size_t)16 * 1048576;         // 16*65536
  unsigned short* finb  = O     + (size_t)16 * 65536;           // 16*1048576 bf16

  k_prep<<<1472, 256, 0, stream>>>(
      x,
      (const float*)d_in[1], (const float*)d_in[2], (const float*)d_in[3],
      (const float*)d_in[4], (const float*)d_in[5], (const float*)d_in[6],
      (const float*)d_in[7], xb, wT);
  k_proj<<<384, 256, 0, stream>>>(xb, wT, P);
  k_qk_vct<<<1408, 256, 0, stream>>>(P, term1, sig, vcT);
  k_scores<<<576, 256, 0, stream>>>(P, term1, sig, finb);
  k_pv_soft<<<1024, 256, 0, stream>>>(finb, vcT, O);
  k_out<<<1024, 256, 0, stream>>>(O, wT + (size_t)6 * 262144, out);
}